// Round 4
// baseline (665.304 us; speedup 1.0000x reference)
//
#include <hip/hip_runtime.h>

typedef unsigned short u16;
typedef unsigned int u32;
typedef __attribute__((ext_vector_type(8))) short short8;
typedef __attribute__((ext_vector_type(8))) _Float16 half8;
typedef __attribute__((ext_vector_type(4))) float f32x4;

#define DEV __device__ __forceinline__

DEV void async_copy16(const void* g, void* l) {
  __builtin_amdgcn_global_load_lds((const __attribute__((address_space(1))) u32*)g,
                                   (__attribute__((address_space(3))) u32*)l, 16, 0, 0);
}
DEV float bf2f(u16 u) { return __uint_as_float(((u32)u) << 16); }
DEV u16 f2bf(float f) {
  u32 x = __float_as_uint(f);
  return (u16)((x + 0x7fffu + ((x >> 16) & 1u)) >> 16);
}
DEV u16 f2h_bits(float f) { _Float16 h = (_Float16)f; return __builtin_bit_cast(u16, h); }
DEV float h2f_bits(u16 b) { return (float)__builtin_bit_cast(_Float16, b); }
DEV float silu_f(float x) { return x / (1.0f + __expf(-x)); }

// Stage one 128x32 f16 tile (8KB) into LDS with XOR chunk pre-swizzle.
DEV void stage_tile(const u16* __restrict__ G, size_t grow_base, int k0, u16* L, int t) {
#pragma unroll
  for (int it = 0; it < 2; ++it) {
    int c = t + it * 256;
    int r = c >> 2, j = c & 3;
    int js = j ^ ((r >> 1) & 3);
    async_copy16(G + ((grow_base + (size_t)r) << 10) + k0 + js * 8,
                 (char*)L + (size_t)c * 16);
  }
}
DEV half8 frag(const u16* L, int rr, int lq) {
  int sw = lq ^ ((rr >> 1) & 3);
  return *(const half8*)((const char*)L + (size_t)rr * 64 + sw * 16);
}
DEV short8 frag_s(const u16* L, int rr, int lq) {
  int sw = lq ^ ((rr >> 1) & 3);
  return *(const short8*)((const char*)L + (size_t)rr * 64 + sw * 16);
}

// ---------------------------------------------------------------------------
// Transpose + convert: Wt[n][k] = bf16(W[k][n])   (for W_out)
// ---------------------------------------------------------------------------
__global__ __launch_bounds__(256) void transpose_k(const float* __restrict__ W,
                                                   u16* __restrict__ Wt,
                                                   int K, int N) {
  __shared__ float s[32][33];
  int t = threadIdx.x;
  int tx = t & 31, ty = t >> 5;
  int ntk = K >> 5;
  int bk = blockIdx.x % ntk, bn = blockIdx.x / ntk;
  int k0 = bk * 32, n0 = bn * 32;
#pragma unroll
  for (int i = 0; i < 4; ++i)
    s[ty + 8 * i][tx] = W[(size_t)(k0 + ty + 8 * i) * N + n0 + tx];
  __syncthreads();
#pragma unroll
  for (int i = 0; i < 4; ++i) {
    int r = ty + 8 * i;
    Wt[(size_t)(n0 + r) * K + k0 + tx] = f2bf(s[tx][r]);
  }
}

// ---------------------------------------------------------------------------
// Split x (f32) into f16 hi/lo planes: X0 = f16(x), X1 = f16((x - X0)*4096).
// ---------------------------------------------------------------------------
__global__ __launch_bounds__(256) void split_x(const float* __restrict__ x,
                                               u16* __restrict__ X0,
                                               u16* __restrict__ X1) {
  int i = (blockIdx.x * 256 + threadIdx.x) * 4;
  float4 v = *(const float4*)&x[i];
  ushort4 h0, h1;
  h0.x = f2h_bits(v.x); h1.x = f2h_bits((v.x - h2f_bits(h0.x)) * 4096.0f);
  h0.y = f2h_bits(v.y); h1.y = f2h_bits((v.y - h2f_bits(h0.y)) * 4096.0f);
  h0.z = f2h_bits(v.z); h1.z = f2h_bits((v.z - h2f_bits(h0.z)) * 4096.0f);
  h0.w = f2h_bits(v.w); h1.w = f2h_bits((v.w - h2f_bits(h0.w)) * 4096.0f);
  *(ushort4*)&X0[i] = h0;
  *(ushort4*)&X1[i] = h1;
}

// ---------------------------------------------------------------------------
// Split + transpose + COLUMN-PERMUTE W_qkv [1024][3072] -> planes [3072][1024].
// src col c -> (c%192)/64*1024 + (c/192)*64 + c%64 : Q cols in [0,1024),
// K in [1024,2048), V in [2048,3072).
// ---------------------------------------------------------------------------
__global__ __launch_bounds__(256) void split_w(const float* __restrict__ W,
                                               u16* __restrict__ W0t,
                                               u16* __restrict__ W1t) {
  __shared__ float s[32][33];
  int t = threadIdx.x;
  int tx = t & 31, ty = t >> 5;
  int bk = blockIdx.x & 31, bn = blockIdx.x >> 5;   // 32 k-tiles, 96 n-tiles
  int k0 = bk * 32, n0 = bn * 32;
#pragma unroll
  for (int i = 0; i < 4; ++i)
    s[ty + 8 * i][tx] = W[(size_t)(k0 + ty + 8 * i) * 3072 + n0 + tx];
  __syncthreads();
#pragma unroll
  for (int i = 0; i < 4; ++i) {
    int r = ty + 8 * i;
    int col = n0 + r;
    int h = col / 192, rem = col - h * 192;
    int cty = rem >> 6, d = rem & 63;
    int pcol = cty * 1024 + h * 64 + d;
    float v = s[tx][r];
    u16 h0 = f2h_bits(v);
    u16 h1 = f2h_bits((v - h2f_bits(h0)) * 4096.0f);
    size_t o = (size_t)pcol * 1024 + k0 + tx;
    W0t[o] = h0;
    W1t[o] = h1;
  }
}

// ---------------------------------------------------------------------------
// GEMM1a: Q/K columns, 3-pass split-f16 MFMA (f32-grade). Round-2 proven
// single-buffer 2-barrier structure: 32KB LDS, ~3 blocks/CU.
// Grid (16, 128): nb in [0,2048). Epilogue: silu -> Qf / Kf (f32).
// ---------------------------------------------------------------------------
__global__ __launch_bounds__(256) void gemm_qk_f16(
    const u16* __restrict__ X0, const u16* __restrict__ X1,
    const u16* __restrict__ W0, const u16* __restrict__ W1,
    const float* __restrict__ bq,
    float* __restrict__ Qf, float* __restrict__ Kf) {
  __shared__ u16 lA0[128 * 32];
  __shared__ u16 lA1[128 * 32];
  __shared__ u16 lB0[128 * 32];
  __shared__ u16 lB1[128 * 32];   // 32KB
  int t = threadIdx.x;
  int w = t >> 6, l = t & 63;
  int wr = w >> 1, wc = w & 1;
  int lr = l & 15, lq = l >> 4;
  int mb = blockIdx.y * 128, nb = blockIdx.x * 128;
  int cty = nb >> 10;                 // 0=Q, 1=K
  f32x4 aM[4][4] = {};
  f32x4 aC[4][4] = {};

  for (int k0 = 0; k0 < 1024; k0 += 32) {
    stage_tile(X0, mb, k0, lA0, t);
    stage_tile(X1, mb, k0, lA1, t);
    stage_tile(W0, nb, k0, lB0, t);
    stage_tile(W1, nb, k0, lB1, t);
    __syncthreads();
    half8 b0[4], b1[4];
#pragma unroll
    for (int nn = 0; nn < 4; ++nn) {
      int rr = wc * 64 + nn * 16 + lr;
      b0[nn] = frag(lB0, rr, lq);
      b1[nn] = frag(lB1, rr, lq);
    }
#pragma unroll
    for (int m = 0; m < 4; ++m) {
      int rr = wr * 64 + m * 16 + lr;
      half8 a0 = frag(lA0, rr, lq);
      half8 a1 = frag(lA1, rr, lq);
#pragma unroll
      for (int nn = 0; nn < 4; ++nn) {
        aM[m][nn] = __builtin_amdgcn_mfma_f32_16x16x32_f16(a0, b0[nn], aM[m][nn], 0, 0, 0);
        aC[m][nn] = __builtin_amdgcn_mfma_f32_16x16x32_f16(a0, b1[nn], aC[m][nn], 0, 0, 0);
        aC[m][nn] = __builtin_amdgcn_mfma_f32_16x16x32_f16(a1, b0[nn], aC[m][nn], 0, 0, 0);
      }
    }
    __syncthreads();
  }

  const float cscale = 2.44140625e-4f;    // 1/4096
  float* dst = (cty == 0) ? Qf : Kf;
#pragma unroll
  for (int nn = 0; nn < 4; ++nn) {
    int col = nb + wc * 64 + nn * 16 + lr;
    int h = (col & 1023) >> 6, d0 = col & 63;
    float bias = bq[h * 192 + cty * 64 + d0];
#pragma unroll
    for (int m = 0; m < 4; ++m)
#pragma unroll
      for (int j = 0; j < 4; ++j) {
        int row = mb + wr * 64 + m * 16 + lq * 4 + j;
        int b = row >> 12, n = row & 4095;
        size_t base = (((size_t)(b * 16 + h) * 4096 + n) << 6) + d0;
        float val = aM[m][nn][j] + aC[m][nn][j] * cscale + bias;
        dst[base] = silu_f(val);
      }
  }
}

// ---------------------------------------------------------------------------
// GEMM1b: V columns, main plane only (bf16-grade output). 16KB LDS.
// Grid (8, 128): pnb = 2048 + blockIdx.x*128.
// ---------------------------------------------------------------------------
__global__ __launch_bounds__(256) void gemm_v_f16(
    const u16* __restrict__ X0, const u16* __restrict__ W0,
    const float* __restrict__ bq, u16* __restrict__ Vb) {
  __shared__ u16 lA0[128 * 32];
  __shared__ u16 lB0[128 * 32];   // 16KB
  int t = threadIdx.x;
  int w = t >> 6, l = t & 63;
  int wr = w >> 1, wc = w & 1;
  int lr = l & 15, lq = l >> 4;
  int mb = blockIdx.y * 128, nb = 2048 + blockIdx.x * 128;
  f32x4 aM[4][4] = {};

  for (int k0 = 0; k0 < 1024; k0 += 32) {
    stage_tile(X0, mb, k0, lA0, t);
    stage_tile(W0, nb, k0, lB0, t);
    __syncthreads();
    half8 b0[4];
#pragma unroll
    for (int nn = 0; nn < 4; ++nn) b0[nn] = frag(lB0, wc * 64 + nn * 16 + lr, lq);
#pragma unroll
    for (int m = 0; m < 4; ++m) {
      half8 a0 = frag(lA0, wr * 64 + m * 16 + lr, lq);
#pragma unroll
      for (int nn = 0; nn < 4; ++nn)
        aM[m][nn] = __builtin_amdgcn_mfma_f32_16x16x32_f16(a0, b0[nn], aM[m][nn], 0, 0, 0);
    }
    __syncthreads();
  }
#pragma unroll
  for (int nn = 0; nn < 4; ++nn) {
    int col = nb + wc * 64 + nn * 16 + lr;
    int h = (col & 1023) >> 6, d0 = col & 63;
    float bias = bq[h * 192 + 128 + d0];
#pragma unroll
    for (int m = 0; m < 4; ++m)
#pragma unroll
      for (int j = 0; j < 4; ++j) {
        int row = mb + wr * 64 + m * 16 + lq * 4 + j;
        int b = row >> 12, n = row & 4095;
        size_t base = (((size_t)(b * 16 + h) * 4096 + n) << 6) + d0;
        Vb[base] = f2bf(aM[m][nn][j] + bias);
      }
  }
}

// ---------------------------------------------------------------------------
// FALLBACK GEMM1 (f32 VALU) — used only if ws_size is too small for planes.
// ---------------------------------------------------------------------------
__global__ __launch_bounds__(256) void gemm_qkv(const float* __restrict__ X,
                                                const float* __restrict__ Wq,
                                                const float* __restrict__ bq,
                                                float* __restrict__ Qf,
                                                float* __restrict__ Kf,
                                                u16* __restrict__ Vb) {
  __shared__ float sA[16 * 132];
  __shared__ float sB[16 * 128];
  int t = threadIdx.x;
  int tm = t >> 4, tn = t & 15;
  int mb = blockIdx.y * 128, nb = blockIdx.x * 128;
  float acc[8][8] = {};

  for (int k0 = 0; k0 < 1024; k0 += 16) {
#pragma unroll
    for (int it = 0; it < 2; ++it) {
      int c = t + it * 256;
      int m = c >> 2, kc = (c & 3) * 4;
      float4 v = *(const float4*)&X[(size_t)(mb + m) * 1024 + k0 + kc];
      sA[(kc + 0) * 132 + m] = v.x;
      sA[(kc + 1) * 132 + m] = v.y;
      sA[(kc + 2) * 132 + m] = v.z;
      sA[(kc + 3) * 132 + m] = v.w;
      int kr = c >> 5, nc = (c & 31) * 4;
      async_copy16(&Wq[(size_t)(k0 + kr) * 3072 + nb + nc], (char*)sB + (size_t)c * 16);
    }
    __syncthreads();
#pragma unroll
    for (int k = 0; k < 16; ++k) {
      float4 a0 = *(const float4*)&sA[k * 132 + tm * 8];
      float4 a1 = *(const float4*)&sA[k * 132 + tm * 8 + 4];
      float4 b0 = *(const float4*)&sB[k * 128 + tn * 8];
      float4 b1 = *(const float4*)&sB[k * 128 + tn * 8 + 4];
      const float av[8] = {a0.x, a0.y, a0.z, a0.w, a1.x, a1.y, a1.z, a1.w};
      const float bv[8] = {b0.x, b0.y, b0.z, b0.w, b1.x, b1.y, b1.z, b1.w};
#pragma unroll
      for (int i = 0; i < 8; ++i)
#pragma unroll
        for (int j = 0; j < 8; ++j) acc[i][j] = fmaf(av[i], bv[j], acc[i][j]);
    }
    __syncthreads();
  }

  int c0 = nb + tn * 8;
  int h = c0 / 192, rem = c0 % 192;
  int ty = rem >> 6, d0 = rem & 63;
  float bb[8];
#pragma unroll
  for (int j = 0; j < 8; ++j) bb[j] = bq[c0 + j];
#pragma unroll
  for (int i = 0; i < 8; ++i) {
    int r = mb + tm * 8 + i;
    int b = r >> 12, n = r & 4095;
    size_t base = (((size_t)(b * 16 + h) * 4096 + n) << 6) + d0;
    if (ty == 2) {
      u16 pk[8];
#pragma unroll
      for (int j = 0; j < 8; ++j) pk[j] = f2bf(acc[i][j] + bb[j]);
      *(short8*)&Vb[base] = *(short8*)pk;
    } else {
      float* dst = (ty == 0) ? Qf : Kf;
#pragma unroll
      for (int j = 0; j < 8; ++j) dst[base + j] = silu_f(acc[i][j] + bb[j]);
    }
  }
}

// ---------------------------------------------------------------------------
// state partials: per (bh, chunk of 512 rows): P[d][e] = sum_n K[n][d]*V[n][e],
// plus ksum partial (fused from the LDS K tile).
// ---------------------------------------------------------------------------
__global__ __launch_bounds__(256) void state_partial(const float* __restrict__ Kf,
                                                     const u16* __restrict__ Vb,
                                                     float* __restrict__ stateP,
                                                     float* __restrict__ ksumP) {
  int bh = blockIdx.y, ch = blockIdx.x, t = threadIdx.x;
  __shared__ float sK[64 * 64];
  __shared__ u16 sV[64 * 64];
  __shared__ float sred[256];
  int n0 = ch * 512;
  size_t base = ((size_t)bh * 4096 + n0) << 6;
  float acc[4][4] = {};
  int te = t & 15, td = t >> 4;
  int kd = t & 63, kq = t >> 6;
  float kacc = 0.0f;

  for (int sc = 0; sc < 8; ++sc) {
    const float* gk = Kf + base + (size_t)sc * 64 * 64;
    const u16* gv = Vb + base + (size_t)sc * 64 * 64;
#pragma unroll
    for (int it = 0; it < 4; ++it)
      async_copy16(gk + (size_t)(t + it * 256) * 4, (char*)sK + (size_t)(t + it * 256) * 16);
#pragma unroll
    for (int it = 0; it < 2; ++it)
      async_copy16(gv + (size_t)(t + it * 256) * 8, (char*)sV + (size_t)(t + it * 256) * 16);
    __syncthreads();
#pragma unroll 4
    for (int n = 0; n < 64; ++n) {
      float4 k4 = *(const float4*)&sK[n * 64 + td * 4];
      const float ka[4] = {k4.x, k4.y, k4.z, k4.w};
      ushort4 vv = *(const ushort4*)&sV[n * 64 + te * 4];
      const float va[4] = {bf2f(vv.x), bf2f(vv.y), bf2f(vv.z), bf2f(vv.w)};
#pragma unroll
      for (int i = 0; i < 4; ++i)
#pragma unroll
        for (int j = 0; j < 4; ++j) acc[i][j] = fmaf(ka[i], va[j], acc[i][j]);
    }
#pragma unroll
    for (int i = 0; i < 16; ++i) kacc += sK[(kq * 16 + i) * 64 + kd];
    __syncthreads();
  }
  size_t pb = ((size_t)bh * 8 + ch) * 4096;
#pragma unroll
  for (int i = 0; i < 4; ++i)
#pragma unroll
    for (int j = 0; j < 4; ++j)
      stateP[pb + (size_t)(td * 4 + i) * 64 + te * 4 + j] = acc[i][j];

  sred[t] = kacc;
  __syncthreads();
  if (t < 64)
    ksumP[((size_t)bh * 8 + ch) * 64 + t] = sred[t] + sred[t + 64] + sred[t + 128] + sred[t + 192];
}

// ---------------------------------------------------------------------------
// attn_out: reduce partials -> state/ksum in LDS; per row: num = q@state,
// den = q.ksum; out = num/(den+eps) -> bf16 row-major [B*N][1024].
// ---------------------------------------------------------------------------
__global__ __launch_bounds__(256) void attn_out(const float* __restrict__ Qf,
                                                const float* __restrict__ stateP,
                                                const float* __restrict__ ksumP,
                                                u16* __restrict__ outb) {
  int bh = blockIdx.y, chnk = blockIdx.x, t = threadIdx.x;
  __shared__ float sS[4096];
  __shared__ float sk[64];
#pragma unroll
  for (int i = 0; i < 16; ++i) {
    int e = t + i * 256;
    float s = 0.0f;
#pragma unroll
    for (int c = 0; c < 8; ++c) s += stateP[((size_t)bh * 8 + c) * 4096 + e];
    sS[e] = s;
  }
  if (t < 64) {
    float s = 0.0f;
#pragma unroll
    for (int c = 0; c < 8; ++c) s += ksumP[((size_t)bh * 8 + c) * 64 + t];
    sk[t] = s;
  }
  __syncthreads();

  int n = chnk * 256 + t;
  size_t qb = ((size_t)bh * 4096 + n) << 6;
  float4 a4[16] = {};
  float den = 0.0f;
#pragma unroll 4
  for (int dd = 0; dd < 16; ++dd) {
    float4 q4 = *(const float4*)&Qf[qb + dd * 4];
    const float qa[4] = {q4.x, q4.y, q4.z, q4.w};
#pragma unroll
    for (int jj = 0; jj < 4; ++jj) {
      int d = dd * 4 + jj;
      float qf = qa[jj];
      den = fmaf(qf, sk[d], den);
      const float4* srow = (const float4*)&sS[d * 64];
#pragma unroll
      for (int e4 = 0; e4 < 16; ++e4) {
        float4 s = srow[e4];
        a4[e4].x = fmaf(qf, s.x, a4[e4].x);
        a4[e4].y = fmaf(qf, s.y, a4[e4].y);
        a4[e4].z = fmaf(qf, s.z, a4[e4].z);
        a4[e4].w = fmaf(qf, s.w, a4[e4].w);
      }
    }
  }
  float rden = 1.0f / (den + 1e-6f);
  int b = bh >> 4, h = bh & 15;
  size_t ob = ((size_t)(b * 4096 + n) << 10) + h * 64;
#pragma unroll
  for (int e4 = 0; e4 < 16; ++e4) {
    ushort4 u;
    u.x = f2bf(a4[e4].x * rden);
    u.y = f2bf(a4[e4].y * rden);
    u.z = f2bf(a4[e4].z * rden);
    u.w = f2bf(a4[e4].w * rden);
    *(ushort4*)&outb[ob + e4 * 4] = u;
  }
}

// ---------------------------------------------------------------------------
// GEMM2 (bf16 MFMA): d_out = out_bf16 @ W_out + b_out.  M=16384,N=1024,K=1024.
// Double-buffered prefetch, 128x128 tile, BK=32 (32KB LDS, >=2 blocks/CU).
// ---------------------------------------------------------------------------
__global__ __launch_bounds__(256) void gemm_out(const u16* __restrict__ A,
                                                const u16* __restrict__ Bt,
                                                const float* __restrict__ bias,
                                                float* __restrict__ C) {
  __shared__ u16 lA[2][128 * 32];
  __shared__ u16 lB[2][128 * 32];
  int t = threadIdx.x;
  int w = t >> 6, l = t & 63;
  int wr = w >> 1, wc = w & 1;
  int lr = l & 15, lq = l >> 4;
  int mb = blockIdx.y * 128, nb = blockIdx.x * 128;
  f32x4 acc[4][4] = {};

  stage_tile(A, mb, 0, lA[0], t);
  stage_tile(Bt, nb, 0, lB[0], t);
  __syncthreads();
  int cur = 0;
  for (int k0 = 0; k0 < 1024; k0 += 32) {
    if (k0 + 32 < 1024) {
      stage_tile(A, mb, k0 + 32, lA[cur ^ 1], t);
      stage_tile(Bt, nb, k0 + 32, lB[cur ^ 1], t);
    }
    short8 af[4], bf[4];
#pragma unroll
    for (int m = 0; m < 4; ++m) af[m] = frag_s(lA[cur], wr * 64 + m * 16 + lr, lq);
#pragma unroll
    for (int nn = 0; nn < 4; ++nn) bf[nn] = frag_s(lB[cur], wc * 64 + nn * 16 + lr, lq);
#pragma unroll
    for (int m = 0; m < 4; ++m)
#pragma unroll
      for (int nn = 0; nn < 4; ++nn)
        acc[m][nn] = __builtin_amdgcn_mfma_f32_16x16x32_bf16(af[m], bf[nn], acc[m][nn], 0, 0, 0);
    __syncthreads();
    cur ^= 1;
  }

#pragma unroll
  for (int m = 0; m < 4; ++m)
#pragma unroll
    for (int nn = 0; nn < 4; ++nn) {
      int col = nb + wc * 64 + nn * 16 + lr;
      float bc = bias[col];
#pragma unroll
      for (int j = 0; j < 4; ++j) {
        int row = mb + wr * 64 + m * 16 + lq * 4 + j;
        C[((size_t)row << 10) + col] = acc[m][nn][j] + bc;
      }
    }
}

// ---------------------------------------------------------------------------
extern "C" void kernel_launch(void* const* d_in, const int* in_sizes, int n_in,
                              void* d_out, int out_size, void* d_ws, size_t ws_size,
                              hipStream_t stream) {
  const float* x    = (const float*)d_in[0];
  const float* Wqkv = (const float*)d_in[1];
  const float* bqkv = (const float*)d_in[2];
  const float* Wout = (const float*)d_in[3];
  const float* bout = (const float*)d_in[4];
  float* out = (float*)d_out;

  char* w = (char*)d_ws;
  const size_t offK  = 0;                      // K f32, 64MB (reused as out_bf16)
  const size_t offV  = offK + 67108864ULL;     // V bf16, 32MB
  const size_t offSP = offV + 33554432ULL;     // state partials f32, 8MB
  const size_t offKP = offSP + 8388608ULL;     // ksum partials, 128KB
  const size_t offWT = offKP + 131072ULL;      // WoutT bf16, 2MB
  const size_t need_base = offWT + 2097152ULL; // 106MB
  const size_t offX0 = need_base;              // X hi f16, 32MB
  const size_t offX1 = offX0 + 33554432ULL;    // X lo f16, 32MB
  const size_t offW0 = offX1 + 33554432ULL;    // Wqkv hi f16 (T, permuted), 6MB
  const size_t offW1 = offW0 + 6291456ULL;     // Wqkv lo f16 (T, permuted), 6MB
  const size_t need_fast = offW1 + 6291456ULL; // ~182MB

  if (ws_size < need_base) return;

  float* Kf     = (float*)(w + offK);
  u16*   outb   = (u16*)(w + offK);
  u16*   Vb     = (u16*)(w + offV);
  float* stateP = (float*)(w + offSP);
  float* ksumP  = (float*)(w + offKP);
  u16*   WoutT  = (u16*)(w + offWT);
  float* Qf     = out;

  transpose_k<<<dim3(1024), dim3(256), 0, stream>>>(Wout, WoutT, 1024, 1024);

  if (ws_size >= need_fast) {
    u16* X0 = (u16*)(w + offX0);
    u16* X1 = (u16*)(w + offX1);
    u16* W0 = (u16*)(w + offW0);
    u16* W1 = (u16*)(w + offW1);
    split_x<<<dim3(16384), dim3(256), 0, stream>>>(x, X0, X1);
    split_w<<<dim3(3072), dim3(256), 0, stream>>>(Wqkv, W0, W1);
    gemm_qk_f16<<<dim3(16, 128), dim3(256), 0, stream>>>(X0, X1, W0, W1, bqkv, Qf, Kf);
    gemm_v_f16<<<dim3(8, 128), dim3(256), 0, stream>>>(X0, W0, bqkv, Vb);
  } else {
    gemm_qkv<<<dim3(24, 128), dim3(256), 0, stream>>>(x, Wqkv, bqkv, Qf, Kf, Vb);
  }

  state_partial<<<dim3(8, 64), dim3(256), 0, stream>>>(Kf, Vb, stateP, ksumP);
  attn_out<<<dim3(16, 64), dim3(256), 0, stream>>>(Qf, stateP, ksumP, outb);
  gemm_out<<<dim3(8, 128), dim3(256), 0, stream>>>(outb, WoutT, bout, out);
}

// Round 5
// 468.989 us; speedup vs baseline: 1.4186x; 1.4186x over previous
//
#include <hip/hip_runtime.h>

typedef unsigned short u16;
typedef unsigned int u32;
typedef __attribute__((ext_vector_type(8))) short short8;
typedef __attribute__((ext_vector_type(8))) _Float16 half8;
typedef __attribute__((ext_vector_type(4))) float f32x4;

#define DEV __device__ __forceinline__

DEV void async_copy16(const void* g, void* l) {
  __builtin_amdgcn_global_load_lds((const __attribute__((address_space(1))) u32*)g,
                                   (__attribute__((address_space(3))) u32*)l, 16, 0, 0);
}
DEV float bf2f(u16 u) { return __uint_as_float(((u32)u) << 16); }
DEV u16 f2bf(float f) {
  u32 x = __float_as_uint(f);
  return (u16)((x + 0x7fffu + ((x >> 16) & 1u)) >> 16);
}
DEV u16 f2h_bits(float f) { _Float16 h = (_Float16)f; return __builtin_bit_cast(u16, h); }
DEV float h2f_bits(u16 b) { return (float)__builtin_bit_cast(_Float16, b); }
DEV float silu_f(float x) { return x / (1.0f + __expf(-x)); }

// Stage one 128x32 f16 tile (8KB) into LDS with XOR chunk pre-swizzle.
DEV void stage_tile(const u16* __restrict__ G, size_t grow_base, int k0, u16* L, int t) {
#pragma unroll
  for (int it = 0; it < 2; ++it) {
    int c = t + it * 256;
    int r = c >> 2, j = c & 3;
    int js = j ^ ((r >> 1) & 3);
    async_copy16(G + ((grow_base + (size_t)r) << 10) + k0 + js * 8,
                 (char*)L + (size_t)c * 16);
  }
}
DEV half8 frag(const u16* L, int rr, int lq) {
  int sw = lq ^ ((rr >> 1) & 3);
  return *(const half8*)((const char*)L + (size_t)rr * 64 + sw * 16);
}
DEV short8 frag_s(const u16* L, int rr, int lq) {
  int sw = lq ^ ((rr >> 1) & 3);
  return *(const short8*)((const char*)L + (size_t)rr * 64 + sw * 16);
}

// ---------------------------------------------------------------------------
// Transpose + convert: Wt[n][k] = bf16(W[k][n])   (for W_out)
// ---------------------------------------------------------------------------
__global__ __launch_bounds__(256) void transpose_k(const float* __restrict__ W,
                                                   u16* __restrict__ Wt,
                                                   int K, int N) {
  __shared__ float s[32][33];
  int t = threadIdx.x;
  int tx = t & 31, ty = t >> 5;
  int ntk = K >> 5;
  int bk = blockIdx.x % ntk, bn = blockIdx.x / ntk;
  int k0 = bk * 32, n0 = bn * 32;
#pragma unroll
  for (int i = 0; i < 4; ++i)
    s[ty + 8 * i][tx] = W[(size_t)(k0 + ty + 8 * i) * N + n0 + tx];
  __syncthreads();
#pragma unroll
  for (int i = 0; i < 4; ++i) {
    int r = ty + 8 * i;
    Wt[(size_t)(n0 + r) * K + k0 + tx] = f2bf(s[tx][r]);
  }
}

// ---------------------------------------------------------------------------
// Split x (f32) into f16 hi/lo planes: X0 = f16(x), X1 = f16((x - X0)*4096).
// ---------------------------------------------------------------------------
__global__ __launch_bounds__(256) void split_x(const float* __restrict__ x,
                                               u16* __restrict__ X0,
                                               u16* __restrict__ X1) {
  int i = (blockIdx.x * 256 + threadIdx.x) * 4;
  float4 v = *(const float4*)&x[i];
  ushort4 h0, h1;
  h0.x = f2h_bits(v.x); h1.x = f2h_bits((v.x - h2f_bits(h0.x)) * 4096.0f);
  h0.y = f2h_bits(v.y); h1.y = f2h_bits((v.y - h2f_bits(h0.y)) * 4096.0f);
  h0.z = f2h_bits(v.z); h1.z = f2h_bits((v.z - h2f_bits(h0.z)) * 4096.0f);
  h0.w = f2h_bits(v.w); h1.w = f2h_bits((v.w - h2f_bits(h0.w)) * 4096.0f);
  *(ushort4*)&X0[i] = h0;
  *(ushort4*)&X1[i] = h1;
}

// ---------------------------------------------------------------------------
// Split + transpose + COLUMN-PERMUTE W_qkv [1024][3072] -> planes [3072][1024].
// src col c -> (c%192)/64*1024 + (c/192)*64 + c%64 : Q cols in [0,1024),
// K in [1024,2048), V in [2048,3072).
// ---------------------------------------------------------------------------
__global__ __launch_bounds__(256) void split_w(const float* __restrict__ W,
                                               u16* __restrict__ W0t,
                                               u16* __restrict__ W1t) {
  __shared__ float s[32][33];
  int t = threadIdx.x;
  int tx = t & 31, ty = t >> 5;
  int bk = blockIdx.x & 31, bn = blockIdx.x >> 5;   // 32 k-tiles, 96 n-tiles
  int k0 = bk * 32, n0 = bn * 32;
#pragma unroll
  for (int i = 0; i < 4; ++i)
    s[ty + 8 * i][tx] = W[(size_t)(k0 + ty + 8 * i) * 3072 + n0 + tx];
  __syncthreads();
#pragma unroll
  for (int i = 0; i < 4; ++i) {
    int r = ty + 8 * i;
    int col = n0 + r;
    int h = col / 192, rem = col - h * 192;
    int cty = rem >> 6, d = rem & 63;
    int pcol = cty * 1024 + h * 64 + d;
    float v = s[tx][r];
    u16 h0 = f2h_bits(v);
    u16 h1 = f2h_bits((v - h2f_bits(h0)) * 4096.0f);
    size_t o = (size_t)pcol * 1024 + k0 + tx;
    W0t[o] = h0;
    W1t[o] = h1;
  }
}

// ---------------------------------------------------------------------------
// GEMM1a: Q/K columns, 3-pass split-f16 MFMA (f32-grade).
// EXACT round-2 code shape: __launch_bounds__(256,2), single fused staging
// loop (shared goA/goB), single-buffer 2-barrier, 32KB LDS.
// Grid (16, 128): nb in [0,2048). Epilogue: silu -> Qf / Kf (f32).
// ---------------------------------------------------------------------------
__global__ __launch_bounds__(256, 2) void gemm_qk_f16(
    const u16* __restrict__ X0, const u16* __restrict__ X1,
    const u16* __restrict__ W0, const u16* __restrict__ W1,
    const float* __restrict__ bq,
    float* __restrict__ Qf, float* __restrict__ Kf) {
  __shared__ u16 lA0[128 * 32];
  __shared__ u16 lA1[128 * 32];
  __shared__ u16 lB0[128 * 32];
  __shared__ u16 lB1[128 * 32];   // 32KB
  int t = threadIdx.x;
  int w = t >> 6, l = t & 63;
  int wr = w >> 1, wc = w & 1;
  int lr = l & 15, lq = l >> 4;
  int mb = blockIdx.y * 128, nb = blockIdx.x * 128;
  int cty = nb >> 10;                 // 0=Q, 1=K
  f32x4 aM[4][4] = {};
  f32x4 aC[4][4] = {};

  for (int k0 = 0; k0 < 1024; k0 += 32) {
#pragma unroll
    for (int it = 0; it < 2; ++it) {
      int c = t + it * 256;               // 16B chunk id, 0..511
      int r = c >> 2, j = c & 3;
      int js = j ^ ((r >> 1) & 3);        // source pre-swizzle (XOR involution)
      size_t goA = (((size_t)(mb + r)) << 10) + k0 + js * 8;
      size_t goB = (((size_t)(nb + r)) << 10) + k0 + js * 8;
      async_copy16(X0 + goA, (char*)lA0 + (size_t)c * 16);
      async_copy16(X1 + goA, (char*)lA1 + (size_t)c * 16);
      async_copy16(W0 + goB, (char*)lB0 + (size_t)c * 16);
      async_copy16(W1 + goB, (char*)lB1 + (size_t)c * 16);
    }
    __syncthreads();
    half8 b0[4], b1[4];
#pragma unroll
    for (int nn = 0; nn < 4; ++nn) {
      int rr = wc * 64 + nn * 16 + lr;
      b0[nn] = frag(lB0, rr, lq);
      b1[nn] = frag(lB1, rr, lq);
    }
#pragma unroll
    for (int m = 0; m < 4; ++m) {
      int rr = wr * 64 + m * 16 + lr;
      half8 a0 = frag(lA0, rr, lq);
      half8 a1 = frag(lA1, rr, lq);
#pragma unroll
      for (int nn = 0; nn < 4; ++nn) {
        aM[m][nn] = __builtin_amdgcn_mfma_f32_16x16x32_f16(a0, b0[nn], aM[m][nn], 0, 0, 0);
        aC[m][nn] = __builtin_amdgcn_mfma_f32_16x16x32_f16(a0, b1[nn], aC[m][nn], 0, 0, 0);
        aC[m][nn] = __builtin_amdgcn_mfma_f32_16x16x32_f16(a1, b0[nn], aC[m][nn], 0, 0, 0);
      }
    }
    __syncthreads();
  }

  const float cscale = 2.44140625e-4f;    // 1/4096
  float* dst = (cty == 0) ? Qf : Kf;
#pragma unroll
  for (int nn = 0; nn < 4; ++nn) {
    int col = nb + wc * 64 + nn * 16 + lr;
    int h = (col & 1023) >> 6, d0 = col & 63;
    float bias = bq[h * 192 + cty * 64 + d0];
#pragma unroll
    for (int m = 0; m < 4; ++m)
#pragma unroll
      for (int j = 0; j < 4; ++j) {
        int row = mb + wr * 64 + m * 16 + lq * 4 + j;
        int b = row >> 12, n = row & 4095;
        size_t base = (((size_t)(b * 16 + h) * 4096 + n) << 6) + d0;
        float val = aM[m][nn][j] + aC[m][nn][j] * cscale + bias;
        dst[base] = silu_f(val);
      }
  }
}

// ---------------------------------------------------------------------------
// GEMM1b: V columns, main plane only (bf16-grade output). 16KB LDS.
// Grid (8, 128): pnb = 2048 + blockIdx.x*128.
// ---------------------------------------------------------------------------
__global__ __launch_bounds__(256) void gemm_v_f16(
    const u16* __restrict__ X0, const u16* __restrict__ W0,
    const float* __restrict__ bq, u16* __restrict__ Vb) {
  __shared__ u16 lA0[128 * 32];
  __shared__ u16 lB0[128 * 32];   // 16KB
  int t = threadIdx.x;
  int w = t >> 6, l = t & 63;
  int wr = w >> 1, wc = w & 1;
  int lr = l & 15, lq = l >> 4;
  int mb = blockIdx.y * 128, nb = 2048 + blockIdx.x * 128;
  f32x4 aM[4][4] = {};

  for (int k0 = 0; k0 < 1024; k0 += 32) {
    stage_tile(X0, mb, k0, lA0, t);
    stage_tile(W0, nb, k0, lB0, t);
    __syncthreads();
    half8 b0[4];
#pragma unroll
    for (int nn = 0; nn < 4; ++nn) b0[nn] = frag(lB0, wc * 64 + nn * 16 + lr, lq);
#pragma unroll
    for (int m = 0; m < 4; ++m) {
      half8 a0 = frag(lA0, wr * 64 + m * 16 + lr, lq);
#pragma unroll
      for (int nn = 0; nn < 4; ++nn)
        aM[m][nn] = __builtin_amdgcn_mfma_f32_16x16x32_f16(a0, b0[nn], aM[m][nn], 0, 0, 0);
    }
    __syncthreads();
  }
#pragma unroll
  for (int nn = 0; nn < 4; ++nn) {
    int col = nb + wc * 64 + nn * 16 + lr;
    int h = (col & 1023) >> 6, d0 = col & 63;
    float bias = bq[h * 192 + 128 + d0];
#pragma unroll
    for (int m = 0; m < 4; ++m)
#pragma unroll
      for (int j = 0; j < 4; ++j) {
        int row = mb + wr * 64 + m * 16 + lq * 4 + j;
        int b = row >> 12, n = row & 4095;
        size_t base = (((size_t)(b * 16 + h) * 4096 + n) << 6) + d0;
        Vb[base] = f2bf(aM[m][nn][j] + bias);
      }
  }
}

// ---------------------------------------------------------------------------
// FALLBACK GEMM1 (f32 VALU) — used only if ws_size is too small for planes.
// ---------------------------------------------------------------------------
__global__ __launch_bounds__(256) void gemm_qkv(const float* __restrict__ X,
                                                const float* __restrict__ Wq,
                                                const float* __restrict__ bq,
                                                float* __restrict__ Qf,
                                                float* __restrict__ Kf,
                                                u16* __restrict__ Vb) {
  __shared__ float sA[16 * 132];
  __shared__ float sB[16 * 128];
  int t = threadIdx.x;
  int tm = t >> 4, tn = t & 15;
  int mb = blockIdx.y * 128, nb = blockIdx.x * 128;
  float acc[8][8] = {};

  for (int k0 = 0; k0 < 1024; k0 += 16) {
#pragma unroll
    for (int it = 0; it < 2; ++it) {
      int c = t + it * 256;
      int m = c >> 2, kc = (c & 3) * 4;
      float4 v = *(const float4*)&X[(size_t)(mb + m) * 1024 + k0 + kc];
      sA[(kc + 0) * 132 + m] = v.x;
      sA[(kc + 1) * 132 + m] = v.y;
      sA[(kc + 2) * 132 + m] = v.z;
      sA[(kc + 3) * 132 + m] = v.w;
      int kr = c >> 5, nc = (c & 31) * 4;
      async_copy16(&Wq[(size_t)(k0 + kr) * 3072 + nb + nc], (char*)sB + (size_t)c * 16);
    }
    __syncthreads();
#pragma unroll
    for (int k = 0; k < 16; ++k) {
      float4 a0 = *(const float4*)&sA[k * 132 + tm * 8];
      float4 a1 = *(const float4*)&sA[k * 132 + tm * 8 + 4];
      float4 b0 = *(const float4*)&sB[k * 128 + tn * 8];
      float4 b1 = *(const float4*)&sB[k * 128 + tn * 8 + 4];
      const float av[8] = {a0.x, a0.y, a0.z, a0.w, a1.x, a1.y, a1.z, a1.w};
      const float bv[8] = {b0.x, b0.y, b0.z, b0.w, b1.x, b1.y, b1.z, b1.w};
#pragma unroll
      for (int i = 0; i < 8; ++i)
#pragma unroll
        for (int j = 0; j < 8; ++j) acc[i][j] = fmaf(av[i], bv[j], acc[i][j]);
    }
    __syncthreads();
  }

  int c0 = nb + tn * 8;
  int h = c0 / 192, rem = c0 % 192;
  int ty = rem >> 6, d0 = rem & 63;
  float bb[8];
#pragma unroll
  for (int j = 0; j < 8; ++j) bb[j] = bq[c0 + j];
#pragma unroll
  for (int i = 0; i < 8; ++i) {
    int r = mb + tm * 8 + i;
    int b = r >> 12, n = r & 4095;
    size_t base = (((size_t)(b * 16 + h) * 4096 + n) << 6) + d0;
    if (ty == 2) {
      u16 pk[8];
#pragma unroll
      for (int j = 0; j < 8; ++j) pk[j] = f2bf(acc[i][j] + bb[j]);
      *(short8*)&Vb[base] = *(short8*)pk;
    } else {
      float* dst = (ty == 0) ? Qf : Kf;
#pragma unroll
      for (int j = 0; j < 8; ++j) dst[base + j] = silu_f(acc[i][j] + bb[j]);
    }
  }
}

// ---------------------------------------------------------------------------
// state partials: per (bh, chunk of 512 rows): P[d][e] = sum_n K[n][d]*V[n][e],
// plus ksum partial (fused from the LDS K tile).
// ---------------------------------------------------------------------------
__global__ __launch_bounds__(256) void state_partial(const float* __restrict__ Kf,
                                                     const u16* __restrict__ Vb,
                                                     float* __restrict__ stateP,
                                                     float* __restrict__ ksumP) {
  int bh = blockIdx.y, ch = blockIdx.x, t = threadIdx.x;
  __shared__ float sK[64 * 64];
  __shared__ u16 sV[64 * 64];
  __shared__ float sred[256];
  int n0 = ch * 512;
  size_t base = ((size_t)bh * 4096 + n0) << 6;
  float acc[4][4] = {};
  int te = t & 15, td = t >> 4;
  int kd = t & 63, kq = t >> 6;
  float kacc = 0.0f;

  for (int sc = 0; sc < 8; ++sc) {
    const float* gk = Kf + base + (size_t)sc * 64 * 64;
    const u16* gv = Vb + base + (size_t)sc * 64 * 64;
#pragma unroll
    for (int it = 0; it < 4; ++it)
      async_copy16(gk + (size_t)(t + it * 256) * 4, (char*)sK + (size_t)(t + it * 256) * 16);
#pragma unroll
    for (int it = 0; it < 2; ++it)
      async_copy16(gv + (size_t)(t + it * 256) * 8, (char*)sV + (size_t)(t + it * 256) * 16);
    __syncthreads();
#pragma unroll 4
    for (int n = 0; n < 64; ++n) {
      float4 k4 = *(const float4*)&sK[n * 64 + td * 4];
      const float ka[4] = {k4.x, k4.y, k4.z, k4.w};
      ushort4 vv = *(const ushort4*)&sV[n * 64 + te * 4];
      const float va[4] = {bf2f(vv.x), bf2f(vv.y), bf2f(vv.z), bf2f(vv.w)};
#pragma unroll
      for (int i = 0; i < 4; ++i)
#pragma unroll
        for (int j = 0; j < 4; ++j) acc[i][j] = fmaf(ka[i], va[j], acc[i][j]);
    }
#pragma unroll
    for (int i = 0; i < 16; ++i) kacc += sK[(kq * 16 + i) * 64 + kd];
    __syncthreads();
  }
  size_t pb = ((size_t)bh * 8 + ch) * 4096;
#pragma unroll
  for (int i = 0; i < 4; ++i)
#pragma unroll
    for (int j = 0; j < 4; ++j)
      stateP[pb + (size_t)(td * 4 + i) * 64 + te * 4 + j] = acc[i][j];

  sred[t] = kacc;
  __syncthreads();
  if (t < 64)
    ksumP[((size_t)bh * 8 + ch) * 64 + t] = sred[t] + sred[t + 64] + sred[t + 128] + sred[t + 192];
}

// ---------------------------------------------------------------------------
// attn_out: reduce partials -> state/ksum in LDS; per row: num = q@state,
// den = q.ksum; out = num/(den+eps) -> bf16 row-major [B*N][1024].
// ---------------------------------------------------------------------------
__global__ __launch_bounds__(256) void attn_out(const float* __restrict__ Qf,
                                                const float* __restrict__ stateP,
                                                const float* __restrict__ ksumP,
                                                u16* __restrict__ outb) {
  int bh = blockIdx.y, chnk = blockIdx.x, t = threadIdx.x;
  __shared__ float sS[4096];
  __shared__ float sk[64];
#pragma unroll
  for (int i = 0; i < 16; ++i) {
    int e = t + i * 256;
    float s = 0.0f;
#pragma unroll
    for (int c = 0; c < 8; ++c) s += stateP[((size_t)bh * 8 + c) * 4096 + e];
    sS[e] = s;
  }
  if (t < 64) {
    float s = 0.0f;
#pragma unroll
    for (int c = 0; c < 8; ++c) s += ksumP[((size_t)bh * 8 + c) * 64 + t];
    sk[t] = s;
  }
  __syncthreads();

  int n = chnk * 256 + t;
  size_t qb = ((size_t)bh * 4096 + n) << 6;
  float4 a4[16] = {};
  float den = 0.0f;
#pragma unroll 4
  for (int dd = 0; dd < 16; ++dd) {
    float4 q4 = *(const float4*)&Qf[qb + dd * 4];
    const float qa[4] = {q4.x, q4.y, q4.z, q4.w};
#pragma unroll
    for (int jj = 0; jj < 4; ++jj) {
      int d = dd * 4 + jj;
      float qf = qa[jj];
      den = fmaf(qf, sk[d], den);
      const float4* srow = (const float4*)&sS[d * 64];
#pragma unroll
      for (int e4 = 0; e4 < 16; ++e4) {
        float4 s = srow[e4];
        a4[e4].x = fmaf(qf, s.x, a4[e4].x);
        a4[e4].y = fmaf(qf, s.y, a4[e4].y);
        a4[e4].z = fmaf(qf, s.z, a4[e4].z);
        a4[e4].w = fmaf(qf, s.w, a4[e4].w);
      }
    }
  }
  float rden = 1.0f / (den + 1e-6f);
  int b = bh >> 4, h = bh & 15;
  size_t ob = ((size_t)(b * 4096 + n) << 10) + h * 64;
#pragma unroll
  for (int e4 = 0; e4 < 16; ++e4) {
    ushort4 u;
    u.x = f2bf(a4[e4].x * rden);
    u.y = f2bf(a4[e4].y * rden);
    u.z = f2bf(a4[e4].z * rden);
    u.w = f2bf(a4[e4].w * rden);
    *(ushort4*)&outb[ob + e4 * 4] = u;
  }
}

// ---------------------------------------------------------------------------
// GEMM2 (bf16 MFMA): d_out = out_bf16 @ W_out + b_out.  M=16384,N=1024,K=1024.
// Double-buffered prefetch, 128x128 tile, BK=32.
// ---------------------------------------------------------------------------
__global__ __launch_bounds__(256) void gemm_out(const u16* __restrict__ A,
                                                const u16* __restrict__ Bt,
                                                const float* __restrict__ bias,
                                                float* __restrict__ C) {
  __shared__ u16 lA[2][128 * 32];
  __shared__ u16 lB[2][128 * 32];
  int t = threadIdx.x;
  int w = t >> 6, l = t & 63;
  int wr = w >> 1, wc = w & 1;
  int lr = l & 15, lq = l >> 4;
  int mb = blockIdx.y * 128, nb = blockIdx.x * 128;
  f32x4 acc[4][4] = {};

  stage_tile(A, mb, 0, lA[0], t);
  stage_tile(Bt, nb, 0, lB[0], t);
  __syncthreads();
  int cur = 0;
  for (int k0 = 0; k0 < 1024; k0 += 32) {
    if (k0 + 32 < 1024) {
      stage_tile(A, mb, k0 + 32, lA[cur ^ 1], t);
      stage_tile(Bt, nb, k0 + 32, lB[cur ^ 1], t);
    }
    short8 af[4], bf[4];
#pragma unroll
    for (int m = 0; m < 4; ++m) af[m] = frag_s(lA[cur], wr * 64 + m * 16 + lr, lq);
#pragma unroll
    for (int nn = 0; nn < 4; ++nn) bf[nn] = frag_s(lB[cur], wc * 64 + nn * 16 + lr, lq);
#pragma unroll
    for (int m = 0; m < 4; ++m)
#pragma unroll
      for (int nn = 0; nn < 4; ++nn)
        acc[m][nn] = __builtin_amdgcn_mfma_f32_16x16x32_bf16(af[m], bf[nn], acc[m][nn], 0, 0, 0);
    __syncthreads();
    cur ^= 1;
  }

#pragma unroll
  for (int m = 0; m < 4; ++m)
#pragma unroll
    for (int nn = 0; nn < 4; ++nn) {
      int col = nb + wc * 64 + nn * 16 + lr;
      float bc = bias[col];
#pragma unroll
      for (int j = 0; j < 4; ++j) {
        int row = mb + wr * 64 + m * 16 + lq * 4 + j;
        C[((size_t)row << 10) + col] = acc[m][nn][j] + bc;
      }
    }
}

// ---------------------------------------------------------------------------
extern "C" void kernel_launch(void* const* d_in, const int* in_sizes, int n_in,
                              void* d_out, int out_size, void* d_ws, size_t ws_size,
                              hipStream_t stream) {
  const float* x    = (const float*)d_in[0];
  const float* Wqkv = (const float*)d_in[1];
  const float* bqkv = (const float*)d_in[2];
  const float* Wout = (const float*)d_in[3];
  const float* bout = (const float*)d_in[4];
  float* out = (float*)d_out;

  char* w = (char*)d_ws;
  const size_t offK  = 0;                      // K f32, 64MB (reused as out_bf16)
  const size_t offV  = offK + 67108864ULL;     // V bf16, 32MB
  const size_t offSP = offV + 33554432ULL;     // state partials f32, 8MB
  const size_t offKP = offSP + 8388608ULL;     // ksum partials, 128KB
  const size_t offWT = offKP + 131072ULL;      // WoutT bf16, 2MB
  const size_t need_base = offWT + 2097152ULL; // 106MB
  const size_t offX0 = need_base;              // X hi f16, 32MB
  const size_t offX1 = offX0 + 33554432ULL;    // X lo f16, 32MB
  const size_t offW0 = offX1 + 33554432ULL;    // Wqkv hi f16 (T, permuted), 6MB
  const size_t offW1 = offW0 + 6291456ULL;     // Wqkv lo f16 (T, permuted), 6MB
  const size_t need_fast = offW1 + 6291456ULL; // ~182MB

  if (ws_size < need_base) return;

  float* Kf     = (float*)(w + offK);
  u16*   outb   = (u16*)(w + offK);
  u16*   Vb     = (u16*)(w + offV);
  float* stateP = (float*)(w + offSP);
  float* ksumP  = (float*)(w + offKP);
  u16*   WoutT  = (u16*)(w + offWT);
  float* Qf     = out;

  transpose_k<<<dim3(1024), dim3(256), 0, stream>>>(Wout, WoutT, 1024, 1024);

  if (ws_size >= need_fast) {
    u16* X0 = (u16*)(w + offX0);
    u16* X1 = (u16*)(w + offX1);
    u16* W0 = (u16*)(w + offW0);
    u16* W1 = (u16*)(w + offW1);
    split_x<<<dim3(16384), dim3(256), 0, stream>>>(x, X0, X1);
    split_w<<<dim3(3072), dim3(256), 0, stream>>>(Wqkv, W0, W1);
    gemm_qk_f16<<<dim3(16, 128), dim3(256), 0, stream>>>(X0, X1, W0, W1, bqkv, Qf, Kf);
    gemm_v_f16<<<dim3(8, 128), dim3(256), 0, stream>>>(X0, W0, bqkv, Vb);
  } else {
    gemm_qkv<<<dim3(24, 128), dim3(256), 0, stream>>>(x, Wqkv, bqkv, Qf, Kf, Vb);
  }

  state_partial<<<dim3(8, 64), dim3(256), 0, stream>>>(Kf, Vb, stateP, ksumP);
  attn_out<<<dim3(16, 64), dim3(256), 0, stream>>>(Qf, stateP, ksumP, outb);
  gemm_out<<<dim3(8, 128), dim3(256), 0, stream>>>(outb, WoutT, bout, out);
}

// Round 6
// 461.492 us; speedup vs baseline: 1.4416x; 1.0162x over previous
//
#include <hip/hip_runtime.h>

typedef unsigned short u16;
typedef unsigned int u32;
typedef __attribute__((ext_vector_type(8))) short short8;
typedef __attribute__((ext_vector_type(8))) _Float16 half8;
typedef __attribute__((ext_vector_type(4))) float f32x4;

#define DEV __device__ __forceinline__

DEV void async_copy16(const void* g, void* l) {
  __builtin_amdgcn_global_load_lds((const __attribute__((address_space(1))) u32*)g,
                                   (__attribute__((address_space(3))) u32*)l, 16, 0, 0);
}
DEV float bf2f(u16 u) { return __uint_as_float(((u32)u) << 16); }
DEV u16 f2bf(float f) {
  u32 x = __float_as_uint(f);
  return (u16)((x + 0x7fffu + ((x >> 16) & 1u)) >> 16);
}
DEV u16 f2h_bits(float f) { _Float16 h = (_Float16)f; return __builtin_bit_cast(u16, h); }
DEV float h2f_bits(u16 b) { return (float)__builtin_bit_cast(_Float16, b); }
DEV float silu_f(float x) { return x / (1.0f + __expf(-x)); }

// Stage one 128x32 f16 tile (8KB) into LDS with XOR chunk pre-swizzle.
DEV void stage_tile(const u16* __restrict__ G, size_t grow_base, int k0, u16* L, int t) {
#pragma unroll
  for (int it = 0; it < 2; ++it) {
    int c = t + it * 256;
    int r = c >> 2, j = c & 3;
    int js = j ^ ((r >> 1) & 3);
    async_copy16(G + ((grow_base + (size_t)r) << 10) + k0 + js * 8,
                 (char*)L + (size_t)c * 16);
  }
}
DEV half8 frag(const u16* L, int rr, int lq) {
  int sw = lq ^ ((rr >> 1) & 3);
  return *(const half8*)((const char*)L + (size_t)rr * 64 + sw * 16);
}
DEV short8 frag_s(const u16* L, int rr, int lq) {
  int sw = lq ^ ((rr >> 1) & 3);
  return *(const short8*)((const char*)L + (size_t)rr * 64 + sw * 16);
}

// ---------------------------------------------------------------------------
// Transpose + convert: Wt[n][k] = bf16(W[k][n])   (for W_out)
// ---------------------------------------------------------------------------
__global__ __launch_bounds__(256) void transpose_k(const float* __restrict__ W,
                                                   u16* __restrict__ Wt,
                                                   int K, int N) {
  __shared__ float s[32][33];
  int t = threadIdx.x;
  int tx = t & 31, ty = t >> 5;
  int ntk = K >> 5;
  int bk = blockIdx.x % ntk, bn = blockIdx.x / ntk;
  int k0 = bk * 32, n0 = bn * 32;
#pragma unroll
  for (int i = 0; i < 4; ++i)
    s[ty + 8 * i][tx] = W[(size_t)(k0 + ty + 8 * i) * N + n0 + tx];
  __syncthreads();
#pragma unroll
  for (int i = 0; i < 4; ++i) {
    int r = ty + 8 * i;
    Wt[(size_t)(n0 + r) * K + k0 + tx] = f2bf(s[tx][r]);
  }
}

// ---------------------------------------------------------------------------
// Split x (f32) into f16 hi/lo planes: X0 = f16(x), X1 = f16((x - X0)*4096).
// ---------------------------------------------------------------------------
__global__ __launch_bounds__(256) void split_x(const float* __restrict__ x,
                                               u16* __restrict__ X0,
                                               u16* __restrict__ X1) {
  int i = (blockIdx.x * 256 + threadIdx.x) * 4;
  float4 v = *(const float4*)&x[i];
  ushort4 h0, h1;
  h0.x = f2h_bits(v.x); h1.x = f2h_bits((v.x - h2f_bits(h0.x)) * 4096.0f);
  h0.y = f2h_bits(v.y); h1.y = f2h_bits((v.y - h2f_bits(h0.y)) * 4096.0f);
  h0.z = f2h_bits(v.z); h1.z = f2h_bits((v.z - h2f_bits(h0.z)) * 4096.0f);
  h0.w = f2h_bits(v.w); h1.w = f2h_bits((v.w - h2f_bits(h0.w)) * 4096.0f);
  *(ushort4*)&X0[i] = h0;
  *(ushort4*)&X1[i] = h1;
}

// ---------------------------------------------------------------------------
// Split + transpose + COLUMN-PERMUTE W_qkv [1024][3072] -> planes [3072][1024].
// src col c -> (c%192)/64*1024 + (c/192)*64 + c%64 : Q cols in [0,1024),
// K in [1024,2048), V in [2048,3072).
// ---------------------------------------------------------------------------
__global__ __launch_bounds__(256) void split_w(const float* __restrict__ W,
                                               u16* __restrict__ W0t,
                                               u16* __restrict__ W1t) {
  __shared__ float s[32][33];
  int t = threadIdx.x;
  int tx = t & 31, ty = t >> 5;
  int bk = blockIdx.x & 31, bn = blockIdx.x >> 5;   // 32 k-tiles, 96 n-tiles
  int k0 = bk * 32, n0 = bn * 32;
#pragma unroll
  for (int i = 0; i < 4; ++i)
    s[ty + 8 * i][tx] = W[(size_t)(k0 + ty + 8 * i) * 3072 + n0 + tx];
  __syncthreads();
#pragma unroll
  for (int i = 0; i < 4; ++i) {
    int r = ty + 8 * i;
    int col = n0 + r;
    int h = col / 192, rem = col - h * 192;
    int cty = rem >> 6, d = rem & 63;
    int pcol = cty * 1024 + h * 64 + d;
    float v = s[tx][r];
    u16 h0 = f2h_bits(v);
    u16 h1 = f2h_bits((v - h2f_bits(h0)) * 4096.0f);
    size_t o = (size_t)pcol * 1024 + k0 + tx;
    W0t[o] = h0;
    W1t[o] = h1;
  }
}

// ---------------------------------------------------------------------------
// GEMM1 (merged): grid (24,128).  Tiles 0-15 = Q/K (3-pass split-f16 MFMA,
// f32-grade, round-5 proven body); tiles 16-23 = V (main pass only -> bf16).
// Single-buffer 2-barrier, 32KB LDS, __launch_bounds__(256,2).
// ---------------------------------------------------------------------------
__global__ __launch_bounds__(256, 2) void gemm_qkv_f16(
    const u16* __restrict__ X0, const u16* __restrict__ X1,
    const u16* __restrict__ W0, const u16* __restrict__ W1,
    const float* __restrict__ bq,
    float* __restrict__ Qf, float* __restrict__ Kf, u16* __restrict__ Vb) {
  __shared__ u16 lA0[128 * 32];
  __shared__ u16 lA1[128 * 32];
  __shared__ u16 lB0[128 * 32];
  __shared__ u16 lB1[128 * 32];   // 32KB
  int t = threadIdx.x;
  int w = t >> 6, l = t & 63;
  int wr = w >> 1, wc = w & 1;
  int lr = l & 15, lq = l >> 4;
  int mb = blockIdx.y * 128, nb = blockIdx.x * 128;
  int cty = nb >> 10;                 // 0=Q, 1=K, 2=V

  if (cty == 2) {
    // ---- V path: main plane only, bf16-grade ----
    f32x4 aM[4][4] = {};
    for (int k0 = 0; k0 < 1024; k0 += 32) {
      stage_tile(X0, mb, k0, lA0, t);
      stage_tile(W0, nb, k0, lB0, t);
      __syncthreads();
      half8 b0[4];
#pragma unroll
      for (int nn = 0; nn < 4; ++nn) b0[nn] = frag(lB0, wc * 64 + nn * 16 + lr, lq);
#pragma unroll
      for (int m = 0; m < 4; ++m) {
        half8 a0 = frag(lA0, wr * 64 + m * 16 + lr, lq);
#pragma unroll
        for (int nn = 0; nn < 4; ++nn)
          aM[m][nn] = __builtin_amdgcn_mfma_f32_16x16x32_f16(a0, b0[nn], aM[m][nn], 0, 0, 0);
      }
      __syncthreads();
    }
#pragma unroll
    for (int nn = 0; nn < 4; ++nn) {
      int col = nb + wc * 64 + nn * 16 + lr;
      int h = (col & 1023) >> 6, d0 = col & 63;
      float bias = bq[h * 192 + 128 + d0];
#pragma unroll
      for (int m = 0; m < 4; ++m)
#pragma unroll
        for (int j = 0; j < 4; ++j) {
          int row = mb + wr * 64 + m * 16 + lq * 4 + j;
          int b = row >> 12, n = row & 4095;
          size_t base = (((size_t)(b * 16 + h) * 4096 + n) << 6) + d0;
          Vb[base] = f2bf(aM[m][nn][j] + bias);
        }
    }
    return;
  }

  // ---- Q/K path: 3-pass split (EXACT round-5 body) ----
  f32x4 aM[4][4] = {};
  f32x4 aC[4][4] = {};

  for (int k0 = 0; k0 < 1024; k0 += 32) {
#pragma unroll
    for (int it = 0; it < 2; ++it) {
      int c = t + it * 256;               // 16B chunk id, 0..511
      int r = c >> 2, j = c & 3;
      int js = j ^ ((r >> 1) & 3);        // source pre-swizzle (XOR involution)
      size_t goA = (((size_t)(mb + r)) << 10) + k0 + js * 8;
      size_t goB = (((size_t)(nb + r)) << 10) + k0 + js * 8;
      async_copy16(X0 + goA, (char*)lA0 + (size_t)c * 16);
      async_copy16(X1 + goA, (char*)lA1 + (size_t)c * 16);
      async_copy16(W0 + goB, (char*)lB0 + (size_t)c * 16);
      async_copy16(W1 + goB, (char*)lB1 + (size_t)c * 16);
    }
    __syncthreads();
    half8 b0[4], b1[4];
#pragma unroll
    for (int nn = 0; nn < 4; ++nn) {
      int rr = wc * 64 + nn * 16 + lr;
      b0[nn] = frag(lB0, rr, lq);
      b1[nn] = frag(lB1, rr, lq);
    }
#pragma unroll
    for (int m = 0; m < 4; ++m) {
      int rr = wr * 64 + m * 16 + lr;
      half8 a0 = frag(lA0, rr, lq);
      half8 a1 = frag(lA1, rr, lq);
#pragma unroll
      for (int nn = 0; nn < 4; ++nn) {
        aM[m][nn] = __builtin_amdgcn_mfma_f32_16x16x32_f16(a0, b0[nn], aM[m][nn], 0, 0, 0);
        aC[m][nn] = __builtin_amdgcn_mfma_f32_16x16x32_f16(a0, b1[nn], aC[m][nn], 0, 0, 0);
        aC[m][nn] = __builtin_amdgcn_mfma_f32_16x16x32_f16(a1, b0[nn], aC[m][nn], 0, 0, 0);
      }
    }
    __syncthreads();
  }

  const float cscale = 2.44140625e-4f;    // 1/4096
  float* dst = (cty == 0) ? Qf : Kf;
#pragma unroll
  for (int nn = 0; nn < 4; ++nn) {
    int col = nb + wc * 64 + nn * 16 + lr;
    int h = (col & 1023) >> 6, d0 = col & 63;
    float bias = bq[h * 192 + cty * 64 + d0];
#pragma unroll
    for (int m = 0; m < 4; ++m)
#pragma unroll
      for (int j = 0; j < 4; ++j) {
        int row = mb + wr * 64 + m * 16 + lq * 4 + j;
        int b = row >> 12, n = row & 4095;
        size_t base = (((size_t)(b * 16 + h) * 4096 + n) << 6) + d0;
        float val = aM[m][nn][j] + aC[m][nn][j] * cscale + bias;
        dst[base] = silu_f(val);
      }
  }
}

// ---------------------------------------------------------------------------
// FALLBACK GEMM1 (f32 VALU) — used only if ws_size is too small for planes.
// ---------------------------------------------------------------------------
__global__ __launch_bounds__(256) void gemm_qkv(const float* __restrict__ X,
                                                const float* __restrict__ Wq,
                                                const float* __restrict__ bq,
                                                float* __restrict__ Qf,
                                                float* __restrict__ Kf,
                                                u16* __restrict__ Vb) {
  __shared__ float sA[16 * 132];
  __shared__ float sB[16 * 128];
  int t = threadIdx.x;
  int tm = t >> 4, tn = t & 15;
  int mb = blockIdx.y * 128, nb = blockIdx.x * 128;
  float acc[8][8] = {};

  for (int k0 = 0; k0 < 1024; k0 += 16) {
#pragma unroll
    for (int it = 0; it < 2; ++it) {
      int c = t + it * 256;
      int m = c >> 2, kc = (c & 3) * 4;
      float4 v = *(const float4*)&X[(size_t)(mb + m) * 1024 + k0 + kc];
      sA[(kc + 0) * 132 + m] = v.x;
      sA[(kc + 1) * 132 + m] = v.y;
      sA[(kc + 2) * 132 + m] = v.z;
      sA[(kc + 3) * 132 + m] = v.w;
      int kr = c >> 5, nc = (c & 31) * 4;
      async_copy16(&Wq[(size_t)(k0 + kr) * 3072 + nb + nc], (char*)sB + (size_t)c * 16);
    }
    __syncthreads();
#pragma unroll
    for (int k = 0; k < 16; ++k) {
      float4 a0 = *(const float4*)&sA[k * 132 + tm * 8];
      float4 a1 = *(const float4*)&sA[k * 132 + tm * 8 + 4];
      float4 b0 = *(const float4*)&sB[k * 128 + tn * 8];
      float4 b1 = *(const float4*)&sB[k * 128 + tn * 8 + 4];
      const float av[8] = {a0.x, a0.y, a0.z, a0.w, a1.x, a1.y, a1.z, a1.w};
      const float bv[8] = {b0.x, b0.y, b0.z, b0.w, b1.x, b1.y, b1.z, b1.w};
#pragma unroll
      for (int i = 0; i < 8; ++i)
#pragma unroll
        for (int j = 0; j < 8; ++j) acc[i][j] = fmaf(av[i], bv[j], acc[i][j]);
    }
    __syncthreads();
  }

  int c0 = nb + tn * 8;
  int h = c0 / 192, rem = c0 % 192;
  int ty = rem >> 6, d0 = rem & 63;
  float bb[8];
#pragma unroll
  for (int j = 0; j < 8; ++j) bb[j] = bq[c0 + j];
#pragma unroll
  for (int i = 0; i < 8; ++i) {
    int r = mb + tm * 8 + i;
    int b = r >> 12, n = r & 4095;
    size_t base = (((size_t)(b * 16 + h) * 4096 + n) << 6) + d0;
    if (ty == 2) {
      u16 pk[8];
#pragma unroll
      for (int j = 0; j < 8; ++j) pk[j] = f2bf(acc[i][j] + bb[j]);
      *(short8*)&Vb[base] = *(short8*)pk;
    } else {
      float* dst = (ty == 0) ? Qf : Kf;
#pragma unroll
      for (int j = 0; j < 8; ++j) dst[base + j] = silu_f(acc[i][j] + bb[j]);
    }
  }
}

// ---------------------------------------------------------------------------
// state partials: per (bh, chunk of 512 rows): P[d][e] = sum_n K[n][d]*V[n][e],
// plus ksum partial (fused from the LDS K tile).
// ---------------------------------------------------------------------------
__global__ __launch_bounds__(256) void state_partial(const float* __restrict__ Kf,
                                                     const u16* __restrict__ Vb,
                                                     float* __restrict__ stateP,
                                                     float* __restrict__ ksumP) {
  int bh = blockIdx.y, ch = blockIdx.x, t = threadIdx.x;
  __shared__ float sK[64 * 64];
  __shared__ u16 sV[64 * 64];
  __shared__ float sred[256];
  int n0 = ch * 512;
  size_t base = ((size_t)bh * 4096 + n0) << 6;
  float acc[4][4] = {};
  int te = t & 15, td = t >> 4;
  int kd = t & 63, kq = t >> 6;
  float kacc = 0.0f;

  for (int sc = 0; sc < 8; ++sc) {
    const float* gk = Kf + base + (size_t)sc * 64 * 64;
    const u16* gv = Vb + base + (size_t)sc * 64 * 64;
#pragma unroll
    for (int it = 0; it < 4; ++it)
      async_copy16(gk + (size_t)(t + it * 256) * 4, (char*)sK + (size_t)(t + it * 256) * 16);
#pragma unroll
    for (int it = 0; it < 2; ++it)
      async_copy16(gv + (size_t)(t + it * 256) * 8, (char*)sV + (size_t)(t + it * 256) * 16);
    __syncthreads();
#pragma unroll 4
    for (int n = 0; n < 64; ++n) {
      float4 k4 = *(const float4*)&sK[n * 64 + td * 4];
      const float ka[4] = {k4.x, k4.y, k4.z, k4.w};
      ushort4 vv = *(const ushort4*)&sV[n * 64 + te * 4];
      const float va[4] = {bf2f(vv.x), bf2f(vv.y), bf2f(vv.z), bf2f(vv.w)};
#pragma unroll
      for (int i = 0; i < 4; ++i)
#pragma unroll
        for (int j = 0; j < 4; ++j) acc[i][j] = fmaf(ka[i], va[j], acc[i][j]);
    }
#pragma unroll
    for (int i = 0; i < 16; ++i) kacc += sK[(kq * 16 + i) * 64 + kd];
    __syncthreads();
  }
  size_t pb = ((size_t)bh * 8 + ch) * 4096;
#pragma unroll
  for (int i = 0; i < 4; ++i)
#pragma unroll
    for (int j = 0; j < 4; ++j)
      stateP[pb + (size_t)(td * 4 + i) * 64 + te * 4 + j] = acc[i][j];

  sred[t] = kacc;
  __syncthreads();
  if (t < 64)
    ksumP[((size_t)bh * 8 + ch) * 64 + t] = sred[t] + sred[t + 64] + sred[t + 128] + sred[t + 192];
}

// ---------------------------------------------------------------------------
// reduce_state: collapse 8 partials -> final state (64x4096) and ksum (64x64).
// ---------------------------------------------------------------------------
__global__ __launch_bounds__(256) void reduce_state(const float* __restrict__ stateP,
                                                    const float* __restrict__ ksumP,
                                                    float* __restrict__ stateF,
                                                    float* __restrict__ ksumF) {
  int bh = blockIdx.x, t = threadIdx.x;
#pragma unroll
  for (int i = 0; i < 16; ++i) {
    int e = t + i * 256;
    float s = 0.0f;
#pragma unroll
    for (int c = 0; c < 8; ++c) s += stateP[((size_t)bh * 8 + c) * 4096 + e];
    stateF[(size_t)bh * 4096 + e] = s;
  }
  if (t < 64) {
    float s = 0.0f;
#pragma unroll
    for (int c = 0; c < 8; ++c) s += ksumP[((size_t)bh * 8 + c) * 64 + t];
    ksumF[(size_t)bh * 64 + t] = s;
  }
}

// ---------------------------------------------------------------------------
// attn_out: load final state/ksum into LDS; per row: num = q@state,
// den = q.ksum; out = num/(den+eps) -> bf16 row-major [B*N][1024].
// ---------------------------------------------------------------------------
__global__ __launch_bounds__(256) void attn_out(const float* __restrict__ Qf,
                                                const float* __restrict__ stateF,
                                                const float* __restrict__ ksumF,
                                                u16* __restrict__ outb) {
  int bh = blockIdx.y, chnk = blockIdx.x, t = threadIdx.x;
  __shared__ float sS[4096];
  __shared__ float sk[64];
#pragma unroll
  for (int i = 0; i < 16; ++i) {
    int e = t + i * 256;
    sS[e] = stateF[(size_t)bh * 4096 + e];
  }
  if (t < 64) sk[t] = ksumF[(size_t)bh * 64 + t];
  __syncthreads();

  int n = chnk * 256 + t;
  size_t qb = ((size_t)bh * 4096 + n) << 6;
  float4 a4[16] = {};
  float den = 0.0f;
#pragma unroll 4
  for (int dd = 0; dd < 16; ++dd) {
    float4 q4 = *(const float4*)&Qf[qb + dd * 4];
    const float qa[4] = {q4.x, q4.y, q4.z, q4.w};
#pragma unroll
    for (int jj = 0; jj < 4; ++jj) {
      int d = dd * 4 + jj;
      float qf = qa[jj];
      den = fmaf(qf, sk[d], den);
      const float4* srow = (const float4*)&sS[d * 64];
#pragma unroll
      for (int e4 = 0; e4 < 16; ++e4) {
        float4 s = srow[e4];
        a4[e4].x = fmaf(qf, s.x, a4[e4].x);
        a4[e4].y = fmaf(qf, s.y, a4[e4].y);
        a4[e4].z = fmaf(qf, s.z, a4[e4].z);
        a4[e4].w = fmaf(qf, s.w, a4[e4].w);
      }
    }
  }
  float rden = 1.0f / (den + 1e-6f);
  int b = bh >> 4, h = bh & 15;
  size_t ob = ((size_t)(b * 4096 + n) << 10) + h * 64;
#pragma unroll
  for (int e4 = 0; e4 < 16; ++e4) {
    ushort4 u;
    u.x = f2bf(a4[e4].x * rden);
    u.y = f2bf(a4[e4].y * rden);
    u.z = f2bf(a4[e4].z * rden);
    u.w = f2bf(a4[e4].w * rden);
    *(ushort4*)&outb[ob + e4 * 4] = u;
  }
}

// ---------------------------------------------------------------------------
// GEMM2 (bf16 MFMA): d_out = out_bf16 @ W_out + b_out.  M=16384,N=1024,K=1024.
// Round-2 proven single-buffer 2-barrier form, 16KB LDS.
// ---------------------------------------------------------------------------
__global__ __launch_bounds__(256) void gemm_out(const u16* __restrict__ A,
                                                const u16* __restrict__ Bt,
                                                const float* __restrict__ bias,
                                                float* __restrict__ C) {
  __shared__ u16 lA[128 * 32];
  __shared__ u16 lB[128 * 32];
  int t = threadIdx.x;
  int w = t >> 6, l = t & 63;
  int wr = w >> 1, wc = w & 1;
  int lr = l & 15, lq = l >> 4;
  int mb = blockIdx.y * 128, nb = blockIdx.x * 128;
  f32x4 acc[4][4] = {};

  for (int k0 = 0; k0 < 1024; k0 += 32) {
    stage_tile(A, mb, k0, lA, t);
    stage_tile(Bt, nb, k0, lB, t);
    __syncthreads();
    short8 af[4], bf[4];
#pragma unroll
    for (int m = 0; m < 4; ++m) af[m] = frag_s(lA, wr * 64 + m * 16 + lr, lq);
#pragma unroll
    for (int nn = 0; nn < 4; ++nn) bf[nn] = frag_s(lB, wc * 64 + nn * 16 + lr, lq);
#pragma unroll
    for (int m = 0; m < 4; ++m)
#pragma unroll
      for (int nn = 0; nn < 4; ++nn)
        acc[m][nn] = __builtin_amdgcn_mfma_f32_16x16x32_bf16(af[m], bf[nn], acc[m][nn], 0, 0, 0);
    __syncthreads();
  }

#pragma unroll
  for (int m = 0; m < 4; ++m)
#pragma unroll
    for (int nn = 0; nn < 4; ++nn) {
      int col = nb + wc * 64 + nn * 16 + lr;
      float bc = bias[col];
#pragma unroll
      for (int j = 0; j < 4; ++j) {
        int row = mb + wr * 64 + m * 16 + lq * 4 + j;
        C[((size_t)row << 10) + col] = acc[m][nn][j] + bc;
      }
    }
}

// ---------------------------------------------------------------------------
extern "C" void kernel_launch(void* const* d_in, const int* in_sizes, int n_in,
                              void* d_out, int out_size, void* d_ws, size_t ws_size,
                              hipStream_t stream) {
  const float* x    = (const float*)d_in[0];
  const float* Wqkv = (const float*)d_in[1];
  const float* bqkv = (const float*)d_in[2];
  const float* Wout = (const float*)d_in[3];
  const float* bout = (const float*)d_in[4];
  float* out = (float*)d_out;

  char* w = (char*)d_ws;
  const size_t offK  = 0;                      // K f32, 64MB (reused as out_bf16)
  const size_t offV  = offK + 67108864ULL;     // V bf16, 32MB
  const size_t offSP = offV + 33554432ULL;     // state partials f32, 8MB
  const size_t offKP = offSP + 8388608ULL;     // ksum partials, 128KB
  const size_t offWT = offKP + 131072ULL;      // WoutT bf16, 2MB
  const size_t offSF = offWT + 2097152ULL;     // state final f32, 1MB
  const size_t offKF = offSF + 1048576ULL;     // ksum final, 16KB
  const size_t need_base = offKF + 16384ULL;   // ~108MB
  const size_t offX0 = need_base;              // X hi f16, 32MB
  const size_t offX1 = offX0 + 33554432ULL;    // X lo f16, 32MB
  const size_t offW0 = offX1 + 33554432ULL;    // Wqkv hi f16 (T, permuted), 6MB
  const size_t offW1 = offW0 + 6291456ULL;     // Wqkv lo f16 (T, permuted), 6MB
  const size_t need_fast = offW1 + 6291456ULL; // ~184MB

  if (ws_size < need_base) return;

  float* Kf     = (float*)(w + offK);
  u16*   outb   = (u16*)(w + offK);
  u16*   Vb     = (u16*)(w + offV);
  float* stateP = (float*)(w + offSP);
  float* ksumP  = (float*)(w + offKP);
  u16*   WoutT  = (u16*)(w + offWT);
  float* stateF = (float*)(w + offSF);
  float* ksumF  = (float*)(w + offKF);
  float* Qf     = out;

  transpose_k<<<dim3(1024), dim3(256), 0, stream>>>(Wout, WoutT, 1024, 1024);

  if (ws_size >= need_fast) {
    u16* X0 = (u16*)(w + offX0);
    u16* X1 = (u16*)(w + offX1);
    u16* W0 = (u16*)(w + offW0);
    u16* W1 = (u16*)(w + offW1);
    split_x<<<dim3(16384), dim3(256), 0, stream>>>(x, X0, X1);
    split_w<<<dim3(3072), dim3(256), 0, stream>>>(Wqkv, W0, W1);
    gemm_qkv_f16<<<dim3(24, 128), dim3(256), 0, stream>>>(X0, X1, W0, W1, bqkv, Qf, Kf, Vb);
  } else {
    gemm_qkv<<<dim3(24, 128), dim3(256), 0, stream>>>(x, Wqkv, bqkv, Qf, Kf, Vb);
  }

  state_partial<<<dim3(8, 64), dim3(256), 0, stream>>>(Kf, Vb, stateP, ksumP);
  reduce_state<<<dim3(64), dim3(256), 0, stream>>>(stateP, ksumP, stateF, ksumF);
  attn_out<<<dim3(16, 64), dim3(256), 0, stream>>>(Qf, stateF, ksumF, outb);
  gemm_out<<<dim3(8, 128), dim3(256), 0, stream>>>(outb, WoutT, bout, out);
}

// Round 7
// 461.204 us; speedup vs baseline: 1.4425x; 1.0006x over previous
//
#include <hip/hip_runtime.h>

typedef unsigned short u16;
typedef unsigned int u32;
typedef __attribute__((ext_vector_type(8))) short short8;
typedef __attribute__((ext_vector_type(8))) _Float16 half8;
typedef __attribute__((ext_vector_type(4))) float f32x4;

#define DEV __device__ __forceinline__

DEV void async_copy16(const void* g, void* l) {
  __builtin_amdgcn_global_load_lds((const __attribute__((address_space(1))) u32*)g,
                                   (__attribute__((address_space(3))) u32*)l, 16, 0, 0);
}
DEV float bf2f(u16 u) { return __uint_as_float(((u32)u) << 16); }
DEV u16 f2bf(float f) {
  u32 x = __float_as_uint(f);
  return (u16)((x + 0x7fffu + ((x >> 16) & 1u)) >> 16);
}
DEV u16 f2h_bits(float f) { _Float16 h = (_Float16)f; return __builtin_bit_cast(u16, h); }
DEV float h2f_bits(u16 b) { return (float)__builtin_bit_cast(_Float16, b); }
DEV float silu_f(float x) { return x / (1.0f + __expf(-x)); }

// Stage one 128x32 f16 tile (8KB) into LDS with XOR chunk pre-swizzle.
DEV void stage_tile(const u16* __restrict__ G, size_t grow_base, int k0, u16* L, int t) {
#pragma unroll
  for (int it = 0; it < 2; ++it) {
    int c = t + it * 256;
    int r = c >> 2, j = c & 3;
    int js = j ^ ((r >> 1) & 3);
    async_copy16(G + ((grow_base + (size_t)r) << 10) + k0 + js * 8,
                 (char*)L + (size_t)c * 16);
  }
}
DEV half8 frag(const u16* L, int rr, int lq) {
  int sw = lq ^ ((rr >> 1) & 3);
  return *(const half8*)((const char*)L + (size_t)rr * 64 + sw * 16);
}
DEV short8 frag_s(const u16* L, int rr, int lq) {
  int sw = lq ^ ((rr >> 1) & 3);
  return *(const short8*)((const char*)L + (size_t)rr * 64 + sw * 16);
}

// ---------------------------------------------------------------------------
// Transpose + convert: Wt[n][k] = bf16(W[k][n])   (for W_out)
// ---------------------------------------------------------------------------
__global__ __launch_bounds__(256) void transpose_k(const float* __restrict__ W,
                                                   u16* __restrict__ Wt,
                                                   int K, int N) {
  __shared__ float s[32][33];
  int t = threadIdx.x;
  int tx = t & 31, ty = t >> 5;
  int ntk = K >> 5;
  int bk = blockIdx.x % ntk, bn = blockIdx.x / ntk;
  int k0 = bk * 32, n0 = bn * 32;
#pragma unroll
  for (int i = 0; i < 4; ++i)
    s[ty + 8 * i][tx] = W[(size_t)(k0 + ty + 8 * i) * N + n0 + tx];
  __syncthreads();
#pragma unroll
  for (int i = 0; i < 4; ++i) {
    int r = ty + 8 * i;
    Wt[(size_t)(n0 + r) * K + k0 + tx] = f2bf(s[tx][r]);
  }
}

// ---------------------------------------------------------------------------
// Split x (f32) into f16 hi/lo planes: X0 = f16(x), X1 = f16((x - X0)*4096).
// ---------------------------------------------------------------------------
__global__ __launch_bounds__(256) void split_x(const float* __restrict__ x,
                                               u16* __restrict__ X0,
                                               u16* __restrict__ X1) {
  int i = (blockIdx.x * 256 + threadIdx.x) * 4;
  float4 v = *(const float4*)&x[i];
  ushort4 h0, h1;
  h0.x = f2h_bits(v.x); h1.x = f2h_bits((v.x - h2f_bits(h0.x)) * 4096.0f);
  h0.y = f2h_bits(v.y); h1.y = f2h_bits((v.y - h2f_bits(h0.y)) * 4096.0f);
  h0.z = f2h_bits(v.z); h1.z = f2h_bits((v.z - h2f_bits(h0.z)) * 4096.0f);
  h0.w = f2h_bits(v.w); h1.w = f2h_bits((v.w - h2f_bits(h0.w)) * 4096.0f);
  *(ushort4*)&X0[i] = h0;
  *(ushort4*)&X1[i] = h1;
}

// ---------------------------------------------------------------------------
// Split + transpose + COLUMN-PERMUTE W_qkv [1024][3072] -> planes [3072][1024].
// src col c -> (c%192)/64*1024 + (c/192)*64 + c%64 : Q cols in [0,1024),
// K in [1024,2048), V in [2048,3072).
// ---------------------------------------------------------------------------
__global__ __launch_bounds__(256) void split_w(const float* __restrict__ W,
                                               u16* __restrict__ W0t,
                                               u16* __restrict__ W1t) {
  __shared__ float s[32][33];
  int t = threadIdx.x;
  int tx = t & 31, ty = t >> 5;
  int bk = blockIdx.x & 31, bn = blockIdx.x >> 5;   // 32 k-tiles, 96 n-tiles
  int k0 = bk * 32, n0 = bn * 32;
#pragma unroll
  for (int i = 0; i < 4; ++i)
    s[ty + 8 * i][tx] = W[(size_t)(k0 + ty + 8 * i) * 3072 + n0 + tx];
  __syncthreads();
#pragma unroll
  for (int i = 0; i < 4; ++i) {
    int r = ty + 8 * i;
    int col = n0 + r;
    int h = col / 192, rem = col - h * 192;
    int cty = rem >> 6, d = rem & 63;
    int pcol = cty * 1024 + h * 64 + d;
    float v = s[tx][r];
    u16 h0 = f2h_bits(v);
    u16 h1 = f2h_bits((v - h2f_bits(h0)) * 4096.0f);
    size_t o = (size_t)pcol * 1024 + k0 + tx;
    W0t[o] = h0;
    W1t[o] = h1;
  }
}

// ---------------------------------------------------------------------------
// GEMM1a: Q/K columns, 3-pass split-f16 MFMA (f32-grade).
// EXACT round-5 proven shape: __launch_bounds__(256,2), fused staging loop,
// single-buffer 2-barrier, 32KB LDS, 104 VGPR, ~21% occ, ~896 TF.
// Grid (16, 128): nb in [0,2048). Epilogue: silu -> Qf / Kf (f32).
// ---------------------------------------------------------------------------
__global__ __launch_bounds__(256, 2) void gemm_qk_f16(
    const u16* __restrict__ X0, const u16* __restrict__ X1,
    const u16* __restrict__ W0, const u16* __restrict__ W1,
    const float* __restrict__ bq,
    float* __restrict__ Qf, float* __restrict__ Kf) {
  __shared__ u16 lA0[128 * 32];
  __shared__ u16 lA1[128 * 32];
  __shared__ u16 lB0[128 * 32];
  __shared__ u16 lB1[128 * 32];   // 32KB
  int t = threadIdx.x;
  int w = t >> 6, l = t & 63;
  int wr = w >> 1, wc = w & 1;
  int lr = l & 15, lq = l >> 4;
  int mb = blockIdx.y * 128, nb = blockIdx.x * 128;
  int cty = nb >> 10;                 // 0=Q, 1=K
  f32x4 aM[4][4] = {};
  f32x4 aC[4][4] = {};

  for (int k0 = 0; k0 < 1024; k0 += 32) {
#pragma unroll
    for (int it = 0; it < 2; ++it) {
      int c = t + it * 256;               // 16B chunk id, 0..511
      int r = c >> 2, j = c & 3;
      int js = j ^ ((r >> 1) & 3);        // source pre-swizzle (XOR involution)
      size_t goA = (((size_t)(mb + r)) << 10) + k0 + js * 8;
      size_t goB = (((size_t)(nb + r)) << 10) + k0 + js * 8;
      async_copy16(X0 + goA, (char*)lA0 + (size_t)c * 16);
      async_copy16(X1 + goA, (char*)lA1 + (size_t)c * 16);
      async_copy16(W0 + goB, (char*)lB0 + (size_t)c * 16);
      async_copy16(W1 + goB, (char*)lB1 + (size_t)c * 16);
    }
    __syncthreads();
    half8 b0[4], b1[4];
#pragma unroll
    for (int nn = 0; nn < 4; ++nn) {
      int rr = wc * 64 + nn * 16 + lr;
      b0[nn] = frag(lB0, rr, lq);
      b1[nn] = frag(lB1, rr, lq);
    }
#pragma unroll
    for (int m = 0; m < 4; ++m) {
      int rr = wr * 64 + m * 16 + lr;
      half8 a0 = frag(lA0, rr, lq);
      half8 a1 = frag(lA1, rr, lq);
#pragma unroll
      for (int nn = 0; nn < 4; ++nn) {
        aM[m][nn] = __builtin_amdgcn_mfma_f32_16x16x32_f16(a0, b0[nn], aM[m][nn], 0, 0, 0);
        aC[m][nn] = __builtin_amdgcn_mfma_f32_16x16x32_f16(a0, b1[nn], aC[m][nn], 0, 0, 0);
        aC[m][nn] = __builtin_amdgcn_mfma_f32_16x16x32_f16(a1, b0[nn], aC[m][nn], 0, 0, 0);
      }
    }
    __syncthreads();
  }

  const float cscale = 2.44140625e-4f;    // 1/4096
  float* dst = (cty == 0) ? Qf : Kf;
#pragma unroll
  for (int nn = 0; nn < 4; ++nn) {
    int col = nb + wc * 64 + nn * 16 + lr;
    int h = (col & 1023) >> 6, d0 = col & 63;
    float bias = bq[h * 192 + cty * 64 + d0];
#pragma unroll
    for (int m = 0; m < 4; ++m)
#pragma unroll
      for (int j = 0; j < 4; ++j) {
        int row = mb + wr * 64 + m * 16 + lq * 4 + j;
        int b = row >> 12, n = row & 4095;
        size_t base = (((size_t)(b * 16 + h) * 4096 + n) << 6) + d0;
        float val = aM[m][nn][j] + aC[m][nn][j] * cscale + bias;
        dst[base] = silu_f(val);
      }
  }
}

// ---------------------------------------------------------------------------
// GEMM1b: V columns, main plane only (bf16-grade output). 16KB LDS.
// Grid (8, 128): pnb = 2048 + blockIdx.x*128.
// ---------------------------------------------------------------------------
__global__ __launch_bounds__(256) void gemm_v_f16(
    const u16* __restrict__ X0, const u16* __restrict__ W0,
    const float* __restrict__ bq, u16* __restrict__ Vb) {
  __shared__ u16 lA0[128 * 32];
  __shared__ u16 lB0[128 * 32];   // 16KB
  int t = threadIdx.x;
  int w = t >> 6, l = t & 63;
  int wr = w >> 1, wc = w & 1;
  int lr = l & 15, lq = l >> 4;
  int mb = blockIdx.y * 128, nb = 2048 + blockIdx.x * 128;
  f32x4 aM[4][4] = {};

  for (int k0 = 0; k0 < 1024; k0 += 32) {
    stage_tile(X0, mb, k0, lA0, t);
    stage_tile(W0, nb, k0, lB0, t);
    __syncthreads();
    half8 b0[4];
#pragma unroll
    for (int nn = 0; nn < 4; ++nn) b0[nn] = frag(lB0, wc * 64 + nn * 16 + lr, lq);
#pragma unroll
    for (int m = 0; m < 4; ++m) {
      half8 a0 = frag(lA0, wr * 64 + m * 16 + lr, lq);
#pragma unroll
      for (int nn = 0; nn < 4; ++nn)
        aM[m][nn] = __builtin_amdgcn_mfma_f32_16x16x32_f16(a0, b0[nn], aM[m][nn], 0, 0, 0);
    }
    __syncthreads();
  }
#pragma unroll
  for (int nn = 0; nn < 4; ++nn) {
    int col = nb + wc * 64 + nn * 16 + lr;
    int h = (col & 1023) >> 6, d0 = col & 63;
    float bias = bq[h * 192 + 128 + d0];
#pragma unroll
    for (int m = 0; m < 4; ++m)
#pragma unroll
      for (int j = 0; j < 4; ++j) {
        int row = mb + wr * 64 + m * 16 + lq * 4 + j;
        int b = row >> 12, n = row & 4095;
        size_t base = (((size_t)(b * 16 + h) * 4096 + n) << 6) + d0;
        Vb[base] = f2bf(aM[m][nn][j] + bias);
      }
  }
}

// ---------------------------------------------------------------------------
// FALLBACK GEMM1 (f32 VALU) — used only if ws_size is too small for planes.
// ---------------------------------------------------------------------------
__global__ __launch_bounds__(256) void gemm_qkv(const float* __restrict__ X,
                                                const float* __restrict__ Wq,
                                                const float* __restrict__ bq,
                                                float* __restrict__ Qf,
                                                float* __restrict__ Kf,
                                                u16* __restrict__ Vb) {
  __shared__ float sA[16 * 132];
  __shared__ float sB[16 * 128];
  int t = threadIdx.x;
  int tm = t >> 4, tn = t & 15;
  int mb = blockIdx.y * 128, nb = blockIdx.x * 128;
  float acc[8][8] = {};

  for (int k0 = 0; k0 < 1024; k0 += 16) {
#pragma unroll
    for (int it = 0; it < 2; ++it) {
      int c = t + it * 256;
      int m = c >> 2, kc = (c & 3) * 4;
      float4 v = *(const float4*)&X[(size_t)(mb + m) * 1024 + k0 + kc];
      sA[(kc + 0) * 132 + m] = v.x;
      sA[(kc + 1) * 132 + m] = v.y;
      sA[(kc + 2) * 132 + m] = v.z;
      sA[(kc + 3) * 132 + m] = v.w;
      int kr = c >> 5, nc = (c & 31) * 4;
      async_copy16(&Wq[(size_t)(k0 + kr) * 3072 + nb + nc], (char*)sB + (size_t)c * 16);
    }
    __syncthreads();
#pragma unroll
    for (int k = 0; k < 16; ++k) {
      float4 a0 = *(const float4*)&sA[k * 132 + tm * 8];
      float4 a1 = *(const float4*)&sA[k * 132 + tm * 8 + 4];
      float4 b0 = *(const float4*)&sB[k * 128 + tn * 8];
      float4 b1 = *(const float4*)&sB[k * 128 + tn * 8 + 4];
      const float av[8] = {a0.x, a0.y, a0.z, a0.w, a1.x, a1.y, a1.z, a1.w};
      const float bv[8] = {b0.x, b0.y, b0.z, b0.w, b1.x, b1.y, b1.z, b1.w};
#pragma unroll
      for (int i = 0; i < 8; ++i)
#pragma unroll
        for (int j = 0; j < 8; ++j) acc[i][j] = fmaf(av[i], bv[j], acc[i][j]);
    }
    __syncthreads();
  }

  int c0 = nb + tn * 8;
  int h = c0 / 192, rem = c0 % 192;
  int ty = rem >> 6, d0 = rem & 63;
  float bb[8];
#pragma unroll
  for (int j = 0; j < 8; ++j) bb[j] = bq[c0 + j];
#pragma unroll
  for (int i = 0; i < 8; ++i) {
    int r = mb + tm * 8 + i;
    int b = r >> 12, n = r & 4095;
    size_t base = (((size_t)(b * 16 + h) * 4096 + n) << 6) + d0;
    if (ty == 2) {
      u16 pk[8];
#pragma unroll
      for (int j = 0; j < 8; ++j) pk[j] = f2bf(acc[i][j] + bb[j]);
      *(short8*)&Vb[base] = *(short8*)pk;
    } else {
      float* dst = (ty == 0) ? Qf : Kf;
#pragma unroll
      for (int j = 0; j < 8; ++j) dst[base + j] = silu_f(acc[i][j] + bb[j]);
    }
  }
}

// ---------------------------------------------------------------------------
// state partials: per (bh, chunk of 512 rows): P[d][e] = sum_n K[n][d]*V[n][e],
// plus ksum partial (fused from the LDS K tile).
// ---------------------------------------------------------------------------
__global__ __launch_bounds__(256) void state_partial(const float* __restrict__ Kf,
                                                     const u16* __restrict__ Vb,
                                                     float* __restrict__ stateP,
                                                     float* __restrict__ ksumP) {
  int bh = blockIdx.y, ch = blockIdx.x, t = threadIdx.x;
  __shared__ float sK[64 * 64];
  __shared__ u16 sV[64 * 64];
  __shared__ float sred[256];
  int n0 = ch * 512;
  size_t base = ((size_t)bh * 4096 + n0) << 6;
  float acc[4][4] = {};
  int te = t & 15, td = t >> 4;
  int kd = t & 63, kq = t >> 6;
  float kacc = 0.0f;

  for (int sc = 0; sc < 8; ++sc) {
    const float* gk = Kf + base + (size_t)sc * 64 * 64;
    const u16* gv = Vb + base + (size_t)sc * 64 * 64;
#pragma unroll
    for (int it = 0; it < 4; ++it)
      async_copy16(gk + (size_t)(t + it * 256) * 4, (char*)sK + (size_t)(t + it * 256) * 16);
#pragma unroll
    for (int it = 0; it < 2; ++it)
      async_copy16(gv + (size_t)(t + it * 256) * 8, (char*)sV + (size_t)(t + it * 256) * 16);
    __syncthreads();
#pragma unroll 4
    for (int n = 0; n < 64; ++n) {
      float4 k4 = *(const float4*)&sK[n * 64 + td * 4];
      const float ka[4] = {k4.x, k4.y, k4.z, k4.w};
      ushort4 vv = *(const ushort4*)&sV[n * 64 + te * 4];
      const float va[4] = {bf2f(vv.x), bf2f(vv.y), bf2f(vv.z), bf2f(vv.w)};
#pragma unroll
      for (int i = 0; i < 4; ++i)
#pragma unroll
        for (int j = 0; j < 4; ++j) acc[i][j] = fmaf(ka[i], va[j], acc[i][j]);
    }
#pragma unroll
    for (int i = 0; i < 16; ++i) kacc += sK[(kq * 16 + i) * 64 + kd];
    __syncthreads();
  }
  size_t pb = ((size_t)bh * 8 + ch) * 4096;
#pragma unroll
  for (int i = 0; i < 4; ++i)
#pragma unroll
    for (int j = 0; j < 4; ++j)
      stateP[pb + (size_t)(td * 4 + i) * 64 + te * 4 + j] = acc[i][j];

  sred[t] = kacc;
  __syncthreads();
  if (t < 64)
    ksumP[((size_t)bh * 8 + ch) * 64 + t] = sred[t] + sred[t + 64] + sred[t + 128] + sred[t + 192];
}

// ---------------------------------------------------------------------------
// reduce_state: collapse 8 partials -> final state (64x4096) and ksum (64x64).
// ---------------------------------------------------------------------------
__global__ __launch_bounds__(256) void reduce_state(const float* __restrict__ stateP,
                                                    const float* __restrict__ ksumP,
                                                    float* __restrict__ stateF,
                                                    float* __restrict__ ksumF) {
  int bh = blockIdx.x, t = threadIdx.x;
#pragma unroll
  for (int i = 0; i < 16; ++i) {
    int e = t + i * 256;
    float s = 0.0f;
#pragma unroll
    for (int c = 0; c < 8; ++c) s += stateP[((size_t)bh * 8 + c) * 4096 + e];
    stateF[(size_t)bh * 4096 + e] = s;
  }
  if (t < 64) {
    float s = 0.0f;
#pragma unroll
    for (int c = 0; c < 8; ++c) s += ksumP[((size_t)bh * 8 + c) * 64 + t];
    ksumF[(size_t)bh * 64 + t] = s;
  }
}

// ---------------------------------------------------------------------------
// attn_out: load final state/ksum into LDS; per row: num = q@state,
// den = q.ksum; out = num/(den+eps) -> bf16 row-major [B*N][1024].
// ---------------------------------------------------------------------------
__global__ __launch_bounds__(256) void attn_out(const float* __restrict__ Qf,
                                                const float* __restrict__ stateF,
                                                const float* __restrict__ ksumF,
                                                u16* __restrict__ outb) {
  int bh = blockIdx.y, chnk = blockIdx.x, t = threadIdx.x;
  __shared__ float sS[4096];
  __shared__ float sk[64];
#pragma unroll
  for (int i = 0; i < 16; ++i) {
    int e = t + i * 256;
    sS[e] = stateF[(size_t)bh * 4096 + e];
  }
  if (t < 64) sk[t] = ksumF[(size_t)bh * 64 + t];
  __syncthreads();

  int n = chnk * 256 + t;
  size_t qb = ((size_t)bh * 4096 + n) << 6;
  float4 a4[16] = {};
  float den = 0.0f;
#pragma unroll 4
  for (int dd = 0; dd < 16; ++dd) {
    float4 q4 = *(const float4*)&Qf[qb + dd * 4];
    const float qa[4] = {q4.x, q4.y, q4.z, q4.w};
#pragma unroll
    for (int jj = 0; jj < 4; ++jj) {
      int d = dd * 4 + jj;
      float qf = qa[jj];
      den = fmaf(qf, sk[d], den);
      const float4* srow = (const float4*)&sS[d * 64];
#pragma unroll
      for (int e4 = 0; e4 < 16; ++e4) {
        float4 s = srow[e4];
        a4[e4].x = fmaf(qf, s.x, a4[e4].x);
        a4[e4].y = fmaf(qf, s.y, a4[e4].y);
        a4[e4].z = fmaf(qf, s.z, a4[e4].z);
        a4[e4].w = fmaf(qf, s.w, a4[e4].w);
      }
    }
  }
  float rden = 1.0f / (den + 1e-6f);
  int b = bh >> 4, h = bh & 15;
  size_t ob = ((size_t)(b * 4096 + n) << 10) + h * 64;
#pragma unroll
  for (int e4 = 0; e4 < 16; ++e4) {
    ushort4 u;
    u.x = f2bf(a4[e4].x * rden);
    u.y = f2bf(a4[e4].y * rden);
    u.z = f2bf(a4[e4].z * rden);
    u.w = f2bf(a4[e4].w * rden);
    *(ushort4*)&outb[ob + e4 * 4] = u;
  }
}

// ---------------------------------------------------------------------------
// GEMM2 (bf16 MFMA): d_out = out_bf16 @ W_out + b_out.  M=16384,N=1024,K=1024.
// Single-buffer 2-barrier form, 16KB LDS.
// ---------------------------------------------------------------------------
__global__ __launch_bounds__(256) void gemm_out(const u16* __restrict__ A,
                                                const u16* __restrict__ Bt,
                                                const float* __restrict__ bias,
                                                float* __restrict__ C) {
  __shared__ u16 lA[128 * 32];
  __shared__ u16 lB[128 * 32];
  int t = threadIdx.x;
  int w = t >> 6, l = t & 63;
  int wr = w >> 1, wc = w & 1;
  int lr = l & 15, lq = l >> 4;
  int mb = blockIdx.y * 128, nb = blockIdx.x * 128;
  f32x4 acc[4][4] = {};

  for (int k0 = 0; k0 < 1024; k0 += 32) {
    stage_tile(A, mb, k0, lA, t);
    stage_tile(Bt, nb, k0, lB, t);
    __syncthreads();
    short8 af[4], bf[4];
#pragma unroll
    for (int m = 0; m < 4; ++m) af[m] = frag_s(lA, wr * 64 + m * 16 + lr, lq);
#pragma unroll
    for (int nn = 0; nn < 4; ++nn) bf[nn] = frag_s(lB, wc * 64 + nn * 16 + lr, lq);
#pragma unroll
    for (int m = 0; m < 4; ++m)
#pragma unroll
      for (int nn = 0; nn < 4; ++nn)
        acc[m][nn] = __builtin_amdgcn_mfma_f32_16x16x32_bf16(af[m], bf[nn], acc[m][nn], 0, 0, 0);
    __syncthreads();
  }

#pragma unroll
  for (int m = 0; m < 4; ++m)
#pragma unroll
    for (int nn = 0; nn < 4; ++nn) {
      int col = nb + wc * 64 + nn * 16 + lr;
      float bc = bias[col];
#pragma unroll
      for (int j = 0; j < 4; ++j) {
        int row = mb + wr * 64 + m * 16 + lq * 4 + j;
        C[((size_t)row << 10) + col] = acc[m][nn][j] + bc;
      }
    }
}

// ---------------------------------------------------------------------------
extern "C" void kernel_launch(void* const* d_in, const int* in_sizes, int n_in,
                              void* d_out, int out_size, void* d_ws, size_t ws_size,
                              hipStream_t stream) {
  const float* x    = (const float*)d_in[0];
  const float* Wqkv = (const float*)d_in[1];
  const float* bqkv = (const float*)d_in[2];
  const float* Wout = (const float*)d_in[3];
  const float* bout = (const float*)d_in[4];
  float* out = (float*)d_out;

  char* w = (char*)d_ws;
  const size_t offK  = 0;                      // K f32, 64MB (reused as out_bf16)
  const size_t offV  = offK + 67108864ULL;     // V bf16, 32MB
  const size_t offSP = offV + 33554432ULL;     // state partials f32, 8MB
  const size_t offKP = offSP + 8388608ULL;     // ksum partials, 128KB
  const size_t offWT = offKP + 131072ULL;      // WoutT bf16, 2MB
  const size_t offSF = offWT + 2097152ULL;     // state final f32, 1MB
  const size_t offKF = offSF + 1048576ULL;     // ksum final, 16KB
  const size_t need_base = offKF + 16384ULL;   // ~108MB
  const size_t offX0 = need_base;              // X hi f16, 32MB
  const size_t offX1 = offX0 + 33554432ULL;    // X lo f16, 32MB
  const size_t offW0 = offX1 + 33554432ULL;    // Wqkv hi f16 (T, permuted), 6MB
  const size_t offW1 = offW0 + 6291456ULL;     // Wqkv lo f16 (T, permuted), 6MB
  const size_t need_fast = offW1 + 6291456ULL; // ~184MB

  if (ws_size < need_base) return;

  float* Kf     = (float*)(w + offK);
  u16*   outb   = (u16*)(w + offK);
  u16*   Vb     = (u16*)(w + offV);
  float* stateP = (float*)(w + offSP);
  float* ksumP  = (float*)(w + offKP);
  u16*   WoutT  = (u16*)(w + offWT);
  float* stateF = (float*)(w + offSF);
  float* ksumF  = (float*)(w + offKF);
  float* Qf     = out;

  transpose_k<<<dim3(1024), dim3(256), 0, stream>>>(Wout, WoutT, 1024, 1024);

  if (ws_size >= need_fast) {
    u16* X0 = (u16*)(w + offX0);
    u16* X1 = (u16*)(w + offX1);
    u16* W0 = (u16*)(w + offW0);
    u16* W1 = (u16*)(w + offW1);
    split_x<<<dim3(16384), dim3(256), 0, stream>>>(x, X0, X1);
    split_w<<<dim3(3072), dim3(256), 0, stream>>>(Wqkv, W0, W1);
    gemm_qk_f16<<<dim3(16, 128), dim3(256), 0, stream>>>(X0, X1, W0, W1, bqkv, Qf, Kf);
    gemm_v_f16<<<dim3(8, 128), dim3(256), 0, stream>>>(X0, W0, bqkv, Vb);
  } else {
    gemm_qkv<<<dim3(24, 128), dim3(256), 0, stream>>>(x, Wqkv, bqkv, Qf, Kf, Vb);
  }

  state_partial<<<dim3(8, 64), dim3(256), 0, stream>>>(Kf, Vb, stateP, ksumP);
  reduce_state<<<dim3(64), dim3(256), 0, stream>>>(stateP, ksumP, stateF, ksumF);
  attn_out<<<dim3(16, 64), dim3(256), 0, stream>>>(Qf, stateF, ksumF, outb);
  gemm_out<<<dim3(8, 128), dim3(256), 0, stream>>>(outb, WoutT, bout, out);
}